// Round 18
// baseline (218.772 us; speedup 1.0000x reference)
//
#include <hip/hip_runtime.h>
#include <hip/hip_bf16.h>

#define NN    4096
#define KNEI  16
#define QPW   4              // query nodes per wave
#define WPB   8              // waves per block (512 threads)
#define BLOCK (WPB * 64)
#define QPB   (WPB * QPW)    // 32 queries per block
#define WIN   1088           // staged sorted-rank window (17 chunks of 64)
#define NCHF  17
#define NEGB  -3.0e38f
#define PACKM 0xFFFFFFC0

typedef float f32x2 __attribute__((ext_vector_type(2)));
typedef int   i32x2 __attribute__((ext_vector_type(2)));

__device__ __forceinline__ int rlane(int v, int l)
{ return __builtin_amdgcn_readlane(v, l); }
__device__ __forceinline__ float rlanef(float v, int l)
{ return __int_as_float(__builtin_amdgcn_readlane(__float_as_int(v), l)); }

template<int CTRL>
__device__ __forceinline__ float rmax_step(float f)
{
    int s_ = __builtin_amdgcn_update_dpp(__float_as_int(f), __float_as_int(f),
                                         CTRL, 0xF, 0xF, false);
    return fmaxf(f, __int_as_float(s_));
}

template<int CTRL>
__device__ __forceinline__ void amax_step(float& f, int& i)
{
    int fs = __builtin_amdgcn_update_dpp(__float_as_int(f), __float_as_int(f),
                                         CTRL, 0xF, 0xF, false);
    int is = __builtin_amdgcn_update_dpp(i, i, CTRL, 0xF, 0xF, false);
    float ff = __int_as_float(fs);
    bool gt = ff > f;
    f = gt ? ff : f;
    i = gt ? is : i;
}

__device__ __forceinline__ void wave_amax(float f, int i, float& M, int& mi)
{
    amax_step<0x111>(f, i); amax_step<0x112>(f, i); amax_step<0x114>(f, i);
    amax_step<0x118>(f, i); amax_step<0x142>(f, i); amax_step<0x143>(f, i);
    M  = rlanef(f, 63);
    mi = rlane(i, 63);
}

__device__ __forceinline__ float row16_sum_dpp(float v)  // lane 16r+15 -> row sum
{
    float f = v;
#define STEPA(CTRL)                                                          \
    { int s_ = __builtin_amdgcn_update_dpp(0, __float_as_int(f),             \
               (CTRL), 0xF, 0xF, true);                                      \
      f += __int_as_float(s_); }
    STEPA(0x111) STEPA(0x112) STEPA(0x114) STEPA(0x118)
#undef STEPA
    return f;
}

__device__ __forceinline__ float bpermf(int abyte, float v)
{ return __int_as_float(__builtin_amdgcn_ds_bpermute(abyte, __float_as_int(v))); }

__device__ __forceinline__ float sel4f(float a, float b, float c, float d, int q)
{
    float lo = (q & 1) ? b : a;
    float hi = (q & 1) ? d : c;
    return (q & 2) ? hi : lo;
}

// purge self (always its scan-lane's packed max, possibly packed 2nd)
#define SELFFIX(bq, sq_, soff)                                               \
    {  int cb_ = __float_as_int(bq) & 63;                                    \
       if ((((cb_) << 6) | (lane ^ cb_)) == (soff)) { (bq) = (sq_); (sq_) = NEGB; } \
       int cs_ = __float_as_int(sq_) & 63;                                   \
       if ((((cs_) << 6) | (lane ^ cs_)) == (soff)) { (sq_) = NEGB; } }

// Scan NCH chunks of the (windowed) sorted array; select top-16 per query.
// src: LDS window (base=blo) or global sorted batch (base=0). selw: wave's
// 64-entry LDS sel region; stores ABSOLUTE sorted ranks. f15: 16th packed
// score of this lane's group-query (valid in all lanes).
template<int NCH>
__device__ __forceinline__ void knn_scan(
    const float4* __restrict__ src, int base, int rq0,
    float x0, float y0, float z0, float x1, float y1, float z1,
    float x2, float y2, float z2, float x3, float y3, float z3,
    int lane, int q, int gt, int* __restrict__ selw, float& f15)
{
    const f32x2 qAx = {x0, x1}, qAy = {y0, y1}, qAz = {z0, z1};
    const f32x2 qBx = {x2, x3}, qBy = {y2, y3}, qBz = {z2, z3};
    const i32x2 M2v = {(int)PACKM, (int)PACKM};

    f32x2 bA = {NEGB, NEGB}, sA = {NEGB, NEGB};
    f32x2 bB = {NEGB, NEGB}, sB = {NEGB, NEGB};

    #pragma unroll
    for (int c = 0; c < NCH; ++c) {
        int off = (c << 6) | (lane ^ c);
        float4 P = src[off];
        f32x2 vx = {P.x, P.x}, vy = {P.y, P.y}, vz = {P.z, P.z}, vw = {P.w, P.w};
        f32x2 dA = __builtin_elementwise_fma(vx, qAx,
                   __builtin_elementwise_fma(vy, qAy,
                   __builtin_elementwise_fma(vz, qAz, vw)));
        f32x2 dB = __builtin_elementwise_fma(vx, qBx,
                   __builtin_elementwise_fma(vy, qBy,
                   __builtin_elementwise_fma(vz, qBz, vw)));
        i32x2 cc = {c, c};
        f32x2 pA = __builtin_bit_cast(f32x2,
                     (__builtin_bit_cast(i32x2, dA) & M2v) | cc);
        f32x2 pB = __builtin_bit_cast(f32x2,
                     (__builtin_bit_cast(i32x2, dB) & M2v) | cc);
        sA = __builtin_elementwise_max(sA, __builtin_elementwise_min(pA, bA));
        bA = __builtin_elementwise_max(bA, pA);
        sB = __builtin_elementwise_max(sB, __builtin_elementwise_min(pB, bB));
        bB = __builtin_elementwise_max(bB, pB);
    }

    float b0 = bA.x, b1 = bA.y, b2 = bB.x, b3 = bB.y;
    float s0 = sA.x, s1 = sA.y, s2 = sB.x, s3 = sB.y;

    const int sq0 = rq0 - base;
    SELFFIX(b0, s0, sq0)
    SELFFIX(b1, s1, sq0 + 1)
    SELFFIX(b2, s2, sq0 + 2)
    SELFFIX(b3, s3, sq0 + 3)

    // redistribute: query q -> lanes 16q..16q+15; lane t owns scan-lanes
    // {t, t+16, t+32, t+48} as slots 0..3
    float pb0, pb1, pb2, pb3, ps0, ps1, ps2, ps3;
    {
        const int ab = gt << 2;
#define PULL(K, PB, PS)                                                      \
        {   int a = ab + ((K) << 6);                                         \
            PB = sel4f(bpermf(a,b0), bpermf(a,b1), bpermf(a,b2), bpermf(a,b3), q); \
            PS = sel4f(bpermf(a,s0), bpermf(a,s1), bpermf(a,s2), bpermf(a,s3), q); \
        }
        PULL(0, pb0, ps0)
        PULL(1, pb1, ps1)
        PULL(2, pb2, ps2)
        PULL(3, pb3, ps3)
#undef PULL
    }

#define REPLAY(qq, xq, yq, zq)                                               \
    {   int wq = __ffsll(ex & (0xFFFFull << ((qq) * 16))) - 1;               \
        int colq = rlane(col, wq);                                           \
        int kq   = rlane(kf,  wq);                                           \
        float sf = NEGB;                                                     \
        int off2 = (lane << 6) | (colq ^ lane);                              \
        if (lane < NCH) {                                                    \
            float4 Pp = src[off2];                                           \
            float scr = fmaf(Pp.x,(xq), fmaf(Pp.y,(yq), fmaf(Pp.z,(zq), Pp.w))); \
            sf = __int_as_float((__float_as_int(scr) & PACKM) | lane);       \
            int j2 = base + off2;                                            \
            if (j2 == rq0 + (qq)) sf = NEGB;                                 \
            const int4* sp = (const int4*)&selw[(qq) << 4];                  \
            int4 sa = sp[0], sb = sp[1], sc = sp[2], sd = sp[3];             \
            if (j2==sa.x || j2==sa.y || j2==sa.z || j2==sa.w) sf = NEGB;     \
            if (j2==sb.x || j2==sb.y || j2==sb.z || j2==sb.w) sf = NEGB;     \
            if (j2==sc.x || j2==sc.y || j2==sc.z || j2==sc.w) sf = NEGB;     \
            if (j2==sd.x || j2==sd.y || j2==sd.z || j2==sd.w) sf = NEGB;     \
        }                                                                    \
        float M1; int i1;                                                    \
        wave_amax(sf, lane, M1, i1);                                         \
        float sf2 = (lane == i1) ? NEGB : sf;                                \
        float M2; int i2;                                                    \
        wave_amax(sf2, lane, M2, i2);                                        \
        bool ow = (lane == (qq) * 16 + (colq & 15));                         \
        if (kq == 0)      { pb0 = ow ? M1 : pb0; ps0 = ow ? M2 : ps0; }      \
        else if (kq == 1) { pb1 = ow ? M1 : pb1; ps1 = ow ? M2 : ps1; }      \
        else if (kq == 2) { pb2 = ow ? M1 : pb2; ps2 = ow ? M2 : ps2; }      \
        else              { pb3 = ow ? M1 : pb3; ps3 = ow ? M2 : ps3; }      \
    }

    const unsigned long long gmask = 0xFFFFull << (q << 4);
    #pragma unroll 1
    for (int r = 0; r < KNEI; ++r) {
        float f = fmaxf(fmaxf(pb0, pb1), fmaxf(pb2, pb3));
        f = rmax_step<0x121>(f); f = rmax_step<0x122>(f);
        f = rmax_step<0x124>(f); f = rmax_step<0x128>(f);
        bool c0 = (pb0 == f), c1 = (pb1 == f), c2 = (pb2 == f), c3 = (pb3 == f);
        unsigned long long m = __ballot(c0 | c1 | c2 | c3);
        int w = __ffsll(m & gmask) - 1;
        bool iwin = (lane == w);
        int kf = c0 ? 0 : (c1 ? 1 : (c2 ? 2 : 3));
        bool o0 = iwin && c0;
        bool o1 = iwin && !c0 && c1;
        bool o2 = iwin && !c0 && !c1 && c2;
        bool o3 = iwin && !c0 && !c1 && !c2;
        int cw  = __float_as_int(f) & 63;                // winner's chunk
        int col = gt + (kf << 4);                        // valid at owner
        int jw  = base + ((cw << 6) | (col ^ cw));       // absolute rank
        if (iwin) selw[(q << 4) + r] = jw;
        if (r == KNEI - 1) f15 = f;
        float pskf = o1 ? ps1 : (o2 ? ps2 : (o3 ? ps3 : ps0));
        bool e = iwin && (pskf == NEGB);
        pb0 = o0 ? ps0 : pb0;  ps0 = o0 ? NEGB : ps0;
        pb1 = o1 ? ps1 : pb1;  ps1 = o1 ? NEGB : ps1;
        pb2 = o2 ? ps2 : pb2;  ps2 = o2 ? NEGB : ps2;
        pb3 = o3 ? ps3 : pb3;  ps3 = o3 ? NEGB : ps3;
        unsigned long long ex = __ballot(e);
        if (ex) {
            if ((ex >>  0) & 0xFFFFull) REPLAY(0, x0, y0, z0)
            if ((ex >> 16) & 0xFFFFull) REPLAY(1, x1, y1, z1)
            if ((ex >> 32) & 0xFFFFull) REPLAY(2, x2, y2, z2)
            if ((ex >> 48) & 0xFFFFull) REPLAY(3, x3, y3, z3)
        }
    }
#undef REPLAY
}

// ---- per-batch bitonic sort by x (key: (x, idx) — deterministic) ----
__global__ __launch_bounds__(1024)
void sort_kernel(const float* __restrict__ coords,
                 float4* __restrict__ spts, int* __restrict__ sids)
{
    __shared__ float kx[NN];
    __shared__ int   ki[NN];
    const int b = blockIdx.x;
    const int t = threadIdx.x;
    const float* cb = coords + (size_t)b * NN * 3;
    for (int i = t; i < NN; i += 1024) { kx[i] = cb[3*i]; ki[i] = i; }
    __syncthreads();
    for (int k = 2; k <= NN; k <<= 1) {
        for (int j = k >> 1; j > 0; j >>= 1) {
            for (int i = t; i < NN; i += 1024) {
                int ixj = i ^ j;
                if (ixj > i) {
                    bool up = ((i & k) == 0);
                    float xa = kx[i], xb = kx[ixj];
                    int   ia = ki[i], ib = ki[ixj];
                    bool sw = up ? (xa > xb || (xa == xb && ia > ib))
                                 : (xa < xb || (xa == xb && ia < ib));
                    if (sw) { kx[i]=xb; kx[ixj]=xa; ki[i]=ib; ki[ixj]=ia; }
                }
            }
            __syncthreads();
        }
    }
    for (int r = t; r < NN; r += 1024) {
        int id = ki[r];
        float x = cb[3*id], y = cb[3*id+1], z = cb[3*id+2];
        spts[(size_t)b*NN + r] = make_float4(x, y, z, -0.5f*(x*x + y*y + z*z));
        sids[(size_t)b*NN + r] = id;
    }
}

__global__ __launch_bounds__(BLOCK, 8)
void protein_enc_kernel(const float4* __restrict__ spts,
                        const int*   __restrict__ sids,
                        const int*   __restrict__ atypes,
                        const int*   __restrict__ rtypes,
                        const float* __restrict__ tpw,
                        const float* __restrict__ aemb,
                        const float* __restrict__ remb,
                        float* __restrict__ out)
{
    __shared__ float4 win[WIN];         // ~17 KB sorted-rank window
    __shared__ float  sW[8 * 32];
    __shared__ int    sel[WPB * 64];    // absolute sorted ranks

    const int tid  = threadIdx.x;
    const int lane = tid & 63;
    const int wv   = tid >> 6;
    const int bpb  = NN / QPB;          // 128
    const int batch    = blockIdx.x / bpb;
    const int nodeBase = (blockIdx.x % bpb) * QPB;

    const float4* gsb = spts + (size_t)batch * NN;

    int blo = nodeBase - 528;
    if (blo < 0) blo = 0;
    blo &= ~63;
    if (blo > NN - WIN) blo = NN - WIN;  // 3008 (64-aligned)

    for (int t = tid; t < WIN; t += BLOCK) win[t] = gsb[blo + t];
    if (tid < 256) sW[tid] = tpw[tid];
    sel[tid] = -1;
    __syncthreads();

    const int rq0 = nodeBase + wv * QPW;         // wave's 4 query ranks
    const float4 Q0 = win[rq0 - blo],   Q1 = win[rq0+1 - blo];
    const float4 Q2 = win[rq0+2 - blo], Q3 = win[rq0+3 - blo];
    const float x0 = Q0.x, y0 = Q0.y, z0 = Q0.z;
    const float x1 = Q1.x, y1 = Q1.y, z1 = Q1.z;
    const float x2 = Q2.x, y2 = Q2.y, z2 = Q2.z;
    const float x3 = Q3.x, y3 = Q3.y, z3 = Q3.z;

    const int q  = lane >> 4;
    const int gt = lane & 15;
    int* selw = &sel[wv * 64];

    float f15 = NEGB;
    knn_scan<NCHF>(win, blo, rq0, x0,y0,z0, x1,y1,z1, x2,y2,z2, x3,y3,z3,
                   lane, q, gt, selw, f15);

    float xq = (q & 2) ? ((q & 1) ? x3 : x2) : ((q & 1) ? x1 : x0);
    float yq = (q & 2) ? ((q & 1) ? y3 : y2) : ((q & 1) ? y1 : y0);
    float zq = (q & 2) ? ((q & 1) ? z3 : z2) : ((q & 1) ? z1 : z0);

    // ---- exactness guarantee: window x-extent must dominate d2_16 ----
    {
        float n2q = xq*xq + yq*yq + zq*zq;
        float d2safe = fmaf(-2.0f, f15, n2q) + 0.125f;   // slack >> pack err
        float xlo = win[0].x, xhi = win[WIN-1].x;
        bool lok = (blo == 0) ||
                   ((xq - xlo) * (xq - xlo) >= d2safe);
        bool rok = (blo + WIN >= NN) ||
                   ((xhi - xq) * (xhi - xq) >= d2safe);
        unsigned long long fb = __ballot(!(lok && rok));
        if (fb) {                        // rare: full exact rescan (global)
            selw[lane] = -1;
            float fd;
            knn_scan<64>(gsb, 0, rq0, x0,y0,z0, x1,y1,z1, x2,y2,z2, x3,y3,z3,
                         lane, q, gt, selw, fd);
        }
    }

    // ---- epilogue: lane (16q+gt) owns edge gt of query q ----
    int selIdx = selw[lane];                     // absolute sorted rank
    float4 P = gsb[selIdx];
    float rx = P.x - xq, ry = P.y - yq, rz = P.z - zq;   // sender - receiver
    float dist = sqrtf(rx*rx + ry*ry + rz*rz);
    float inv  = 1.0f / (dist + 1e-8f);
    float hx = rx * inv, hy = ry * inv, hz = rz * inv;
    float cu = fminf(dist / 10.0f, 1.0f);
    float A = expf(cu * cu * -32.0f);
    float E = expf(cu * (64.0f / 7.0f));
    const float K[8] = {1.0f, 0.5204501f, 0.0733697f, 0.00280164f,
                        2.897772e-05f, 8.11857e-08f, 6.16130e-11f,
                        1.2664166e-14f};
    float gg[8];
    float t = A, ssum = A;
    gg[0] = A;
    #pragma unroll
    for (int v = 1; v < 8; ++v) { t *= E; gg[v] = t * K[v]; ssum += gg[v]; }
    float is = 1.0f / ssum;
    float S[24];
    #pragma unroll
    for (int v = 0; v < 8; ++v) {
        float rbv = gg[v] * is;
        S[3*v]   = rbv * hx;
        S[3*v+1] = rbv * hy;
        S[3*v+2] = rbv * hz;
    }
    #pragma unroll
    for (int t2 = 0; t2 < 24; ++t2) S[t2] = row16_sum_dpp(S[t2]);

    float wcol[8];
    #pragma unroll
    for (int v = 0; v < 8; ++v) wcol[v] = sW[32*v + (lane & 31)];

    const float scale = 0.036084391824351613f;   // 1/(16*sqrt(3))
    const float4 z4 = make_float4(0.f, 0.f, 0.f, 0.f);

    #pragma unroll
    for (int qq = 0; qq < QPW; ++qq) {
        const int gid = sids[(size_t)batch * NN + rq0 + qq];
        const int gq  = batch * NN + gid;
        float sg[24];
        #pragma unroll
        for (int t2 = 0; t2 < 24; ++t2) sg[t2] = rlanef(S[t2], 16 * qq + 15);

        float* onode = out + (size_t)gq * 464;
        float4* o4 = (float4*)onode;
        if (lane < 16)       o4[lane] = z4;          // ch 0..63
        else if (lane < 36)  o4[lane + 24] = z4;     // ch 160..239

        if (lane < 32) {
            float a0 = 0.f, a1 = 0.f, a2 = 0.f;
            #pragma unroll
            for (int v = 0; v < 8; ++v) {
                a0 = fmaf(wcol[v], sg[3*v],   a0);
                a1 = fmaf(wcol[v], sg[3*v+1], a1);
                a2 = fmaf(wcol[v], sg[3*v+2], a2);
            }
            onode[64 + 3*lane]     = a0 * scale;
            onode[64 + 3*lane + 1] = a1 * scale;
            onode[64 + 3*lane + 2] = a2 * scale;
        }

        const int at = atypes[gq];
        const int rt = rtypes[gq];
        if (lane < 56) {
            float4 v = (lane < 28)
                ? ((const float4*)(aemb + 112*at))[lane]
                : ((const float4*)(remb + 112*rt))[lane - 28];
            o4[60 + lane] = v;
        }
    }
}

extern "C" void kernel_launch(void* const* d_in, const int* in_sizes, int n_in,
                              void* d_out, int out_size, void* d_ws, size_t ws_size,
                              hipStream_t stream)
{
    const float* coords = (const float*)d_in[0];
    const int*   at     = (const int*)  d_in[1];
    const int*   rt     = (const int*)  d_in[2];
    const float* tpw    = (const float*)d_in[3];
    const float* ae     = (const float*)d_in[4];
    const float* re     = (const float*)d_in[5];
    float* out = (float*)d_out;

    const int B = in_sizes[1] / NN;                  // 8
    float4* spts = (float4*)d_ws;
    int*    sids = (int*)((char*)d_ws + (size_t)B * NN * sizeof(float4));

    sort_kernel<<<B, 1024, 0, stream>>>(coords, spts, sids);
    protein_enc_kernel<<<B * (NN / QPB), BLOCK, 0, stream>>>(
        spts, sids, at, rt, tpw, ae, re, out);
}

// Round 19
// 125.715 us; speedup vs baseline: 1.7402x; 1.7402x over previous
//
#include <hip/hip_runtime.h>
#include <hip/hip_bf16.h>

#define NN    4096
#define KNEI  16
#define QPW   4              // query nodes per wave
#define WPB   8              // waves per block (512 threads)
#define BLOCK (WPB * 64)
#define QPB   (WPB * QPW)    // 32 queries per block
#define WIN   1088           // staged rank window (17 chunks of 64)
#define NCHF  17
#define NBKT  256
#define NEGB  -3.0e38f
#define PACKM 0xFFFFFFC0

typedef float f32x2 __attribute__((ext_vector_type(2)));
typedef int   i32x2 __attribute__((ext_vector_type(2)));

__device__ __forceinline__ int rlane(int v, int l)
{ return __builtin_amdgcn_readlane(v, l); }
__device__ __forceinline__ float rlanef(float v, int l)
{ return __int_as_float(__builtin_amdgcn_readlane(__float_as_int(v), l)); }

template<int CTRL>
__device__ __forceinline__ float rmax_step(float f)
{
    int s_ = __builtin_amdgcn_update_dpp(__float_as_int(f), __float_as_int(f),
                                         CTRL, 0xF, 0xF, false);
    return fmaxf(f, __int_as_float(s_));
}

template<int CTRL>
__device__ __forceinline__ void amax_step(float& f, int& i)
{
    int fs = __builtin_amdgcn_update_dpp(__float_as_int(f), __float_as_int(f),
                                         CTRL, 0xF, 0xF, false);
    int is = __builtin_amdgcn_update_dpp(i, i, CTRL, 0xF, 0xF, false);
    float ff = __int_as_float(fs);
    bool gt = ff > f;
    f = gt ? ff : f;
    i = gt ? is : i;
}

__device__ __forceinline__ void wave_amax(float f, int i, float& M, int& mi)
{
    amax_step<0x111>(f, i); amax_step<0x112>(f, i); amax_step<0x114>(f, i);
    amax_step<0x118>(f, i); amax_step<0x142>(f, i); amax_step<0x143>(f, i);
    M  = rlanef(f, 63);
    mi = rlane(i, 63);
}

__device__ __forceinline__ float row16_sum_dpp(float v)  // lane 16r+15 -> row sum
{
    float f = v;
#define STEPA(CTRL)                                                          \
    { int s_ = __builtin_amdgcn_update_dpp(0, __float_as_int(f),             \
               (CTRL), 0xF, 0xF, true);                                      \
      f += __int_as_float(s_); }
    STEPA(0x111) STEPA(0x112) STEPA(0x114) STEPA(0x118)
#undef STEPA
    return f;
}

__device__ __forceinline__ float bpermf(int abyte, float v)
{ return __int_as_float(__builtin_amdgcn_ds_bpermute(abyte, __float_as_int(v))); }

__device__ __forceinline__ float sel4f(float a, float b, float c, float d, int q)
{
    float lo = (q & 1) ? b : a;
    float hi = (q & 1) ? d : c;
    return (q & 2) ? hi : lo;
}

// purge self (always its scan-lane's packed max, possibly packed 2nd)
#define SELFFIX(bq, sq_, soff)                                               \
    {  int cb_ = __float_as_int(bq) & 63;                                    \
       if ((((cb_) << 6) | (lane ^ cb_)) == (soff)) { (bq) = (sq_); (sq_) = NEGB; } \
       int cs_ = __float_as_int(sq_) & 63;                                   \
       if ((((cs_) << 6) | (lane ^ cs_)) == (soff)) { (sq_) = NEGB; } }

// ---------------- hot windowed scan (LDS window, 17 chunks) ----------------
__device__ __forceinline__ void knn_scan_win(
    const float4* __restrict__ win, int blo, int rq0,
    float x0, float y0, float z0, float x1, float y1, float z1,
    float x2, float y2, float z2, float x3, float y3, float z3,
    int lane, int q, int gt, int* __restrict__ selw, float& f15)
{
    const f32x2 qAx = {x0, x1}, qAy = {y0, y1}, qAz = {z0, z1};
    const f32x2 qBx = {x2, x3}, qBy = {y2, y3}, qBz = {z2, z3};
    const i32x2 M2v = {(int)PACKM, (int)PACKM};

    f32x2 bA = {NEGB, NEGB}, sA = {NEGB, NEGB};
    f32x2 bB = {NEGB, NEGB}, sB = {NEGB, NEGB};

    #pragma unroll
    for (int c = 0; c < NCHF; ++c) {
        int off = (c << 6) | (lane ^ c);
        float4 P = win[off];
        f32x2 vx = {P.x, P.x}, vy = {P.y, P.y}, vz = {P.z, P.z}, vw = {P.w, P.w};
        f32x2 dA = __builtin_elementwise_fma(vx, qAx,
                   __builtin_elementwise_fma(vy, qAy,
                   __builtin_elementwise_fma(vz, qAz, vw)));
        f32x2 dB = __builtin_elementwise_fma(vx, qBx,
                   __builtin_elementwise_fma(vy, qBy,
                   __builtin_elementwise_fma(vz, qBz, vw)));
        i32x2 cc = {c, c};
        f32x2 pA = __builtin_bit_cast(f32x2,
                     (__builtin_bit_cast(i32x2, dA) & M2v) | cc);
        f32x2 pB = __builtin_bit_cast(f32x2,
                     (__builtin_bit_cast(i32x2, dB) & M2v) | cc);
        sA = __builtin_elementwise_max(sA, __builtin_elementwise_min(pA, bA));
        bA = __builtin_elementwise_max(bA, pA);
        sB = __builtin_elementwise_max(sB, __builtin_elementwise_min(pB, bB));
        bB = __builtin_elementwise_max(bB, pB);
    }

    float b0 = bA.x, b1 = bA.y, b2 = bB.x, b3 = bB.y;
    float s0 = sA.x, s1 = sA.y, s2 = sB.x, s3 = sB.y;

    const int sq0 = rq0 - blo;
    SELFFIX(b0, s0, sq0)
    SELFFIX(b1, s1, sq0 + 1)
    SELFFIX(b2, s2, sq0 + 2)
    SELFFIX(b3, s3, sq0 + 3)

    float pb0, pb1, pb2, pb3, ps0, ps1, ps2, ps3;
    {
        const int ab = gt << 2;
#define PULL(K, PB, PS)                                                      \
        {   int a = ab + ((K) << 6);                                         \
            PB = sel4f(bpermf(a,b0), bpermf(a,b1), bpermf(a,b2), bpermf(a,b3), q); \
            PS = sel4f(bpermf(a,s0), bpermf(a,s1), bpermf(a,s2), bpermf(a,s3), q); \
        }
        PULL(0, pb0, ps0)
        PULL(1, pb1, ps1)
        PULL(2, pb2, ps2)
        PULL(3, pb3, ps3)
#undef PULL
    }

#define REPLAYW(qq, xq, yq, zq)                                              \
    {   int wq = __ffsll(ex & (0xFFFFull << ((qq) * 16))) - 1;               \
        int colq = rlane(col, wq);                                           \
        int kq   = rlane(kf,  wq);                                           \
        float sf = NEGB;                                                     \
        int off2 = (lane << 6) | (colq ^ lane);                              \
        if (lane < NCHF) {                                                   \
            float4 Pp = win[off2];                                           \
            float scr = fmaf(Pp.x,(xq), fmaf(Pp.y,(yq), fmaf(Pp.z,(zq), Pp.w))); \
            sf = __int_as_float((__float_as_int(scr) & PACKM) | lane);       \
            int j2 = blo + off2;                                             \
            if (j2 == rq0 + (qq)) sf = NEGB;                                 \
            const int4* sp = (const int4*)&selw[(qq) << 4];                  \
            int4 sa = sp[0], sb = sp[1], sc = sp[2], sd = sp[3];             \
            if (j2==sa.x || j2==sa.y || j2==sa.z || j2==sa.w) sf = NEGB;     \
            if (j2==sb.x || j2==sb.y || j2==sb.z || j2==sb.w) sf = NEGB;     \
            if (j2==sc.x || j2==sc.y || j2==sc.z || j2==sc.w) sf = NEGB;     \
            if (j2==sd.x || j2==sd.y || j2==sd.z || j2==sd.w) sf = NEGB;     \
        }                                                                    \
        float M1; int i1;                                                    \
        wave_amax(sf, lane, M1, i1);                                         \
        float sf2 = (lane == i1) ? NEGB : sf;                                \
        float M2; int i2;                                                    \
        wave_amax(sf2, lane, M2, i2);                                        \
        bool ow = (lane == (qq) * 16 + (colq & 15));                         \
        if (kq == 0)      { pb0 = ow ? M1 : pb0; ps0 = ow ? M2 : ps0; }      \
        else if (kq == 1) { pb1 = ow ? M1 : pb1; ps1 = ow ? M2 : ps1; }      \
        else if (kq == 2) { pb2 = ow ? M1 : pb2; ps2 = ow ? M2 : ps2; }      \
        else              { pb3 = ow ? M1 : pb3; ps3 = ow ? M2 : ps3; }      \
    }

    const unsigned long long gmask = 0xFFFFull << (q << 4);
    #pragma unroll 1
    for (int r = 0; r < KNEI; ++r) {
        float f = fmaxf(fmaxf(pb0, pb1), fmaxf(pb2, pb3));
        f = rmax_step<0x121>(f); f = rmax_step<0x122>(f);
        f = rmax_step<0x124>(f); f = rmax_step<0x128>(f);
        bool c0 = (pb0 == f), c1 = (pb1 == f), c2 = (pb2 == f), c3 = (pb3 == f);
        unsigned long long m = __ballot(c0 | c1 | c2 | c3);
        int w = __ffsll(m & gmask) - 1;
        bool iwin = (lane == w);
        int kf = c0 ? 0 : (c1 ? 1 : (c2 ? 2 : 3));
        bool o0 = iwin && c0;
        bool o1 = iwin && !c0 && c1;
        bool o2 = iwin && !c0 && !c1 && c2;
        bool o3 = iwin && !c0 && !c1 && !c2;
        int cw  = __float_as_int(f) & 63;
        int col = gt + (kf << 4);
        int jw  = blo + ((cw << 6) | (col ^ cw));
        if (iwin) selw[(q << 4) + r] = jw;
        if (r == KNEI - 1) f15 = f;
        float pskf = o1 ? ps1 : (o2 ? ps2 : (o3 ? ps3 : ps0));
        bool e = iwin && (pskf == NEGB);
        pb0 = o0 ? ps0 : pb0;  ps0 = o0 ? NEGB : ps0;
        pb1 = o1 ? ps1 : pb1;  ps1 = o1 ? NEGB : ps1;
        pb2 = o2 ? ps2 : pb2;  ps2 = o2 ? NEGB : ps2;
        pb3 = o3 ? ps3 : pb3;  ps3 = o3 ? NEGB : ps3;
        unsigned long long ex = __ballot(e);
        if (ex) {
            if ((ex >>  0) & 0xFFFFull) REPLAYW(0, x0, y0, z0)
            if ((ex >> 16) & 0xFFFFull) REPLAYW(1, x1, y1, z1)
            if ((ex >> 32) & 0xFFFFull) REPLAYW(2, x2, y2, z2)
            if ((ex >> 48) & 0xFFFFull) REPLAYW(3, x3, y3, z3)
        }
    }
#undef REPLAYW
}

// ------------- cold exact full scan (global, noinline-isolated) -------------
__device__ __attribute__((noinline)) void knn_scan_full(
    const float4* __restrict__ gsb, int rq0,
    float x0, float y0, float z0, float x1, float y1, float z1,
    float x2, float y2, float z2, float x3, float y3, float z3,
    int lane, int q, int gt, int* __restrict__ selw)
{
    const f32x2 qAx = {x0, x1}, qAy = {y0, y1}, qAz = {z0, z1};
    const f32x2 qBx = {x2, x3}, qBy = {y2, y3}, qBz = {z2, z3};
    const i32x2 M2v = {(int)PACKM, (int)PACKM};

    f32x2 bA = {NEGB, NEGB}, sA = {NEGB, NEGB};
    f32x2 bB = {NEGB, NEGB}, sB = {NEGB, NEGB};

    #pragma unroll 4
    for (int c = 0; c < 64; ++c) {
        int off = (c << 6) | (lane ^ c);
        float4 P = gsb[off];
        f32x2 vx = {P.x, P.x}, vy = {P.y, P.y}, vz = {P.z, P.z}, vw = {P.w, P.w};
        f32x2 dA = __builtin_elementwise_fma(vx, qAx,
                   __builtin_elementwise_fma(vy, qAy,
                   __builtin_elementwise_fma(vz, qAz, vw)));
        f32x2 dB = __builtin_elementwise_fma(vx, qBx,
                   __builtin_elementwise_fma(vy, qBy,
                   __builtin_elementwise_fma(vz, qBz, vw)));
        i32x2 cc = {c, c};
        f32x2 pA = __builtin_bit_cast(f32x2,
                     (__builtin_bit_cast(i32x2, dA) & M2v) | cc);
        f32x2 pB = __builtin_bit_cast(f32x2,
                     (__builtin_bit_cast(i32x2, dB) & M2v) | cc);
        sA = __builtin_elementwise_max(sA, __builtin_elementwise_min(pA, bA));
        bA = __builtin_elementwise_max(bA, pA);
        sB = __builtin_elementwise_max(sB, __builtin_elementwise_min(pB, bB));
        bB = __builtin_elementwise_max(bB, pB);
    }

    float b0 = bA.x, b1 = bA.y, b2 = bB.x, b3 = bB.y;
    float s0 = sA.x, s1 = sA.y, s2 = sB.x, s3 = sB.y;

    SELFFIX(b0, s0, rq0)
    SELFFIX(b1, s1, rq0 + 1)
    SELFFIX(b2, s2, rq0 + 2)
    SELFFIX(b3, s3, rq0 + 3)

    float pb0, pb1, pb2, pb3, ps0, ps1, ps2, ps3;
    {
        const int ab = gt << 2;
#define PULL(K, PB, PS)                                                      \
        {   int a = ab + ((K) << 6);                                         \
            PB = sel4f(bpermf(a,b0), bpermf(a,b1), bpermf(a,b2), bpermf(a,b3), q); \
            PS = sel4f(bpermf(a,s0), bpermf(a,s1), bpermf(a,s2), bpermf(a,s3), q); \
        }
        PULL(0, pb0, ps0)
        PULL(1, pb1, ps1)
        PULL(2, pb2, ps2)
        PULL(3, pb3, ps3)
#undef PULL
    }

#define REPLAYF(qq, xq, yq, zq)                                              \
    {   int wq = __ffsll(ex & (0xFFFFull << ((qq) * 16))) - 1;               \
        int colq = rlane(col, wq);                                           \
        int kq   = rlane(kf,  wq);                                           \
        int j2 = (lane << 6) | (colq ^ lane);                                \
        float4 Pp = gsb[j2];                                                 \
        float scr = fmaf(Pp.x,(xq), fmaf(Pp.y,(yq), fmaf(Pp.z,(zq), Pp.w))); \
        float sf = __int_as_float((__float_as_int(scr) & PACKM) | lane);     \
        if (j2 == rq0 + (qq)) sf = NEGB;                                     \
        const int4* sp = (const int4*)&selw[(qq) << 4];                      \
        int4 sa = sp[0], sb = sp[1], sc = sp[2], sd = sp[3];                 \
        if (j2==sa.x || j2==sa.y || j2==sa.z || j2==sa.w) sf = NEGB;         \
        if (j2==sb.x || j2==sb.y || j2==sb.z || j2==sb.w) sf = NEGB;         \
        if (j2==sc.x || j2==sc.y || j2==sc.z || j2==sc.w) sf = NEGB;         \
        if (j2==sd.x || j2==sd.y || j2==sd.z || j2==sd.w) sf = NEGB;         \
        float M1; int i1;                                                    \
        wave_amax(sf, lane, M1, i1);                                         \
        float sf2 = (lane == i1) ? NEGB : sf;                                \
        float M2; int i2;                                                    \
        wave_amax(sf2, lane, M2, i2);                                        \
        bool ow = (lane == (qq) * 16 + (colq & 15));                         \
        if (kq == 0)      { pb0 = ow ? M1 : pb0; ps0 = ow ? M2 : ps0; }      \
        else if (kq == 1) { pb1 = ow ? M1 : pb1; ps1 = ow ? M2 : ps1; }      \
        else if (kq == 2) { pb2 = ow ? M1 : pb2; ps2 = ow ? M2 : ps2; }      \
        else              { pb3 = ow ? M1 : pb3; ps3 = ow ? M2 : ps3; }      \
    }

    const unsigned long long gmask = 0xFFFFull << (q << 4);
    #pragma unroll 1
    for (int r = 0; r < KNEI; ++r) {
        float f = fmaxf(fmaxf(pb0, pb1), fmaxf(pb2, pb3));
        f = rmax_step<0x121>(f); f = rmax_step<0x122>(f);
        f = rmax_step<0x124>(f); f = rmax_step<0x128>(f);
        bool c0 = (pb0 == f), c1 = (pb1 == f), c2 = (pb2 == f), c3 = (pb3 == f);
        unsigned long long m = __ballot(c0 | c1 | c2 | c3);
        int w = __ffsll(m & gmask) - 1;
        bool iwin = (lane == w);
        int kf = c0 ? 0 : (c1 ? 1 : (c2 ? 2 : 3));
        bool o0 = iwin && c0;
        bool o1 = iwin && !c0 && c1;
        bool o2 = iwin && !c0 && !c1 && c2;
        bool o3 = iwin && !c0 && !c1 && !c2;
        int cw  = __float_as_int(f) & 63;
        int col = gt + (kf << 4);
        int jw  = (cw << 6) | (col ^ cw);
        if (iwin) selw[(q << 4) + r] = jw;
        float pskf = o1 ? ps1 : (o2 ? ps2 : (o3 ? ps3 : ps0));
        bool e = iwin && (pskf == NEGB);
        pb0 = o0 ? ps0 : pb0;  ps0 = o0 ? NEGB : ps0;
        pb1 = o1 ? ps1 : pb1;  ps1 = o1 ? NEGB : ps1;
        pb2 = o2 ? ps2 : pb2;  ps2 = o2 ? NEGB : ps2;
        pb3 = o3 ? ps3 : pb3;  ps3 = o3 ? NEGB : ps3;
        unsigned long long ex = __ballot(e);
        if (ex) {
            if ((ex >>  0) & 0xFFFFull) REPLAYF(0, x0, y0, z0)
            if ((ex >> 16) & 0xFFFFull) REPLAYF(1, x1, y1, z1)
            if ((ex >> 32) & 0xFFFFull) REPLAYF(2, x2, y2, z2)
            if ((ex >> 48) & 0xFFFFull) REPLAYF(3, x3, y3, z3)
        }
    }
#undef REPLAYF
}

// ---- per-batch counting sort by x into 256 buckets (deterministic sets) ----
__global__ __launch_bounds__(1024)
void bucket_kernel(const float* __restrict__ coords,
                   float4* __restrict__ spts, int* __restrict__ sids,
                   float* __restrict__ eHi, float* __restrict__ eLo)
{
    __shared__ float sx[NN];
    __shared__ int   hist[NBKT + 1];
    __shared__ float rmin[16], rmax[16];

    const int b = blockIdx.x;
    const int t = threadIdx.x;
    const int lane = t & 63;
    const int wvv  = t >> 6;
    const float* cb = coords + (size_t)b * NN * 3;

    float lmin = 3.0e38f, lmax = -3.0e38f;
    for (int i = t; i < NN; i += 1024) {
        float x = cb[3*i];
        sx[i] = x;
        lmin = fminf(lmin, x);
        lmax = fmaxf(lmax, x);
    }
    #pragma unroll
    for (int o = 32; o >= 1; o >>= 1) {
        lmin = fminf(lmin, __shfl_xor(lmin, o));
        lmax = fmaxf(lmax, __shfl_xor(lmax, o));
    }
    if (lane == 0) { rmin[wvv] = lmin; rmax[wvv] = lmax; }
    if (t <= NBKT) hist[t] = 0;
    __syncthreads();
    if (t == 0) {
        float a = rmin[0], c = rmax[0];
        for (int k = 1; k < 16; ++k) { a = fminf(a, rmin[k]); c = fmaxf(c, rmax[k]); }
        rmin[0] = a; rmax[0] = c;
    }
    __syncthreads();
    const float xmin = rmin[0];
    const float bw   = fmaxf((rmax[0] - xmin) * (1.0f / NBKT), 1e-6f);
    const float ibw  = 1.0f / bw;

    for (int i = t; i < NN; i += 1024) {
        int bk = (int)((sx[i] - xmin) * ibw);
        bk = min(NBKT - 1, max(0, bk));
        atomicAdd(&hist[bk + 1], 1);
    }
    __syncthreads();
    if (t == 0) {
        int acc = 0;
        for (int k = 0; k <= NBKT; ++k) { acc += hist[k]; hist[k] = acc; }
        // hist[k] now = start offset of bucket k (hist[0]=0 preserved by acc order)
    }
    __syncthreads();
    // NOTE: after the loop above hist[k] = inclusive prefix of counts shifted by
    // one (start of bucket k), because counts were stored at hist[bk+1].
    for (int i = t; i < NN; i += 1024) {
        float x = sx[i];
        int bk = (int)((x - xmin) * ibw);
        bk = min(NBKT - 1, max(0, bk));
        int pos = atomicAdd(&hist[bk], 1);
        float y = cb[3*i + 1], z = cb[3*i + 2];
        size_t o = (size_t)b * NN + pos;
        spts[o] = make_float4(x, y, z, -0.5f * (x*x + y*y + z*z));
        sids[o] = i;
        eHi[o] = xmin + (bk + 1) * bw;
        eLo[o] = xmin + bk * bw;
    }
}

__global__ __launch_bounds__(BLOCK, 8)
void protein_enc_kernel(const float4* __restrict__ spts,
                        const int*   __restrict__ sids,
                        const float* __restrict__ eHi,
                        const float* __restrict__ eLo,
                        const int*   __restrict__ atypes,
                        const int*   __restrict__ rtypes,
                        const float* __restrict__ tpw,
                        const float* __restrict__ aemb,
                        const float* __restrict__ remb,
                        float* __restrict__ out)
{
    __shared__ float4 win[WIN];         // ~17 KB rank window
    __shared__ float  sW[8 * 32];
    __shared__ int    sel[WPB * 64];    // absolute ranks

    const int tid  = threadIdx.x;
    const int lane = tid & 63;
    const int wv   = tid >> 6;
    const int bpb  = NN / QPB;          // 128
    const int batch    = blockIdx.x / bpb;
    const int nodeBase = (blockIdx.x % bpb) * QPB;

    const float4* gsb = spts + (size_t)batch * NN;

    int blo = nodeBase - 528;
    if (blo < 0) blo = 0;
    blo &= ~63;
    if (blo > NN - WIN) blo = NN - WIN;

    for (int t = tid; t < WIN; t += BLOCK) win[t] = gsb[blo + t];
    if (tid < 256) sW[tid] = tpw[tid];
    sel[tid] = -1;
    __syncthreads();

    const int rq0 = nodeBase + wv * QPW;
    const float4 Q0 = win[rq0 - blo],   Q1 = win[rq0+1 - blo];
    const float4 Q2 = win[rq0+2 - blo], Q3 = win[rq0+3 - blo];
    const float x0 = Q0.x, y0 = Q0.y, z0 = Q0.z;
    const float x1 = Q1.x, y1 = Q1.y, z1 = Q1.z;
    const float x2 = Q2.x, y2 = Q2.y, z2 = Q2.z;
    const float x3 = Q3.x, y3 = Q3.y, z3 = Q3.z;

    const int q  = lane >> 4;
    const int gt = lane & 15;
    int* selw = &sel[wv * 64];

    float f15 = NEGB;
    knn_scan_win(win, blo, rq0, x0,y0,z0, x1,y1,z1, x2,y2,z2, x3,y3,z3,
                 lane, q, gt, selw, f15);

    float xq = (q & 2) ? ((q & 1) ? x3 : x2) : ((q & 1) ? x1 : x0);
    float yq = (q & 2) ? ((q & 1) ? y3 : y2) : ((q & 1) ? y1 : y0);
    float zq = (q & 2) ? ((q & 1) ? z3 : z2) : ((q & 1) ? z1 : z0);

    // ---- exactness: bucket-edge bounds must dominate d2_16 ----
    bool didFull = false;
    {
        float n2q = xq*xq + yq*yq + zq*zq;
        float d2safe = fmaf(-2.0f, f15, n2q) + 0.125f;
        bool lok = (blo == 0);
        if (!lok) {
            float xloB = eHi[(size_t)batch * NN + blo - 1];
            float dl = xq - xloB;
            lok = (dl > 0.0f) && (dl * dl >= d2safe);
        }
        bool rok = (blo + WIN >= NN);
        if (!rok) {
            float xhiB = eLo[(size_t)batch * NN + blo + WIN];
            float dr = xhiB - xq;
            rok = (dr > 0.0f) && (dr * dr >= d2safe);
        }
        unsigned long long fb = __ballot(!(lok && rok));
        if (fb) {                        // rare: exact full rescan from global
            selw[lane] = -1;
            knn_scan_full(gsb, rq0, x0,y0,z0, x1,y1,z1, x2,y2,z2, x3,y3,z3,
                          lane, q, gt, selw);
            didFull = true;
        }
    }

    // ---- epilogue: lane (16q+gt) owns edge gt of query q ----
    int selIdx = selw[lane];
    float4 P = didFull ? gsb[selIdx] : win[selIdx - blo];
    float rx = P.x - xq, ry = P.y - yq, rz = P.z - zq;
    float dist = sqrtf(rx*rx + ry*ry + rz*rz);
    float inv  = 1.0f / (dist + 1e-8f);
    float hx = rx * inv, hy = ry * inv, hz = rz * inv;
    float cu = fminf(dist / 10.0f, 1.0f);
    float A = expf(cu * cu * -32.0f);
    float E = expf(cu * (64.0f / 7.0f));
    const float K[8] = {1.0f, 0.5204501f, 0.0733697f, 0.00280164f,
                        2.897772e-05f, 8.11857e-08f, 6.16130e-11f,
                        1.2664166e-14f};
    float gg[8];
    float t = A, ssum = A;
    gg[0] = A;
    #pragma unroll
    for (int v = 1; v < 8; ++v) { t *= E; gg[v] = t * K[v]; ssum += gg[v]; }
    float is = 1.0f / ssum;
    float S[24];
    #pragma unroll
    for (int v = 0; v < 8; ++v) {
        float rbv = gg[v] * is;
        S[3*v]   = rbv * hx;
        S[3*v+1] = rbv * hy;
        S[3*v+2] = rbv * hz;
    }
    #pragma unroll
    for (int t2 = 0; t2 < 24; ++t2) S[t2] = row16_sum_dpp(S[t2]);

    float wcol[8];
    #pragma unroll
    for (int v = 0; v < 8; ++v) wcol[v] = sW[32*v + (lane & 31)];

    const float scale = 0.036084391824351613f;   // 1/(16*sqrt(3))
    const float4 z4 = make_float4(0.f, 0.f, 0.f, 0.f);

    #pragma unroll
    for (int qq = 0; qq < QPW; ++qq) {
        const int gid = sids[(size_t)batch * NN + rq0 + qq];
        const int gq  = batch * NN + gid;
        float sg[24];
        #pragma unroll
        for (int t2 = 0; t2 < 24; ++t2) sg[t2] = rlanef(S[t2], 16 * qq + 15);

        float* onode = out + (size_t)gq * 464;
        float4* o4 = (float4*)onode;
        if (lane < 16)       o4[lane] = z4;          // ch 0..63
        else if (lane < 36)  o4[lane + 24] = z4;     // ch 160..239

        if (lane < 32) {
            float a0 = 0.f, a1 = 0.f, a2 = 0.f;
            #pragma unroll
            for (int v = 0; v < 8; ++v) {
                a0 = fmaf(wcol[v], sg[3*v],   a0);
                a1 = fmaf(wcol[v], sg[3*v+1], a1);
                a2 = fmaf(wcol[v], sg[3*v+2], a2);
            }
            onode[64 + 3*lane]     = a0 * scale;
            onode[64 + 3*lane + 1] = a1 * scale;
            onode[64 + 3*lane + 2] = a2 * scale;
        }

        const int at = atypes[gq];
        const int rt = rtypes[gq];
        if (lane < 56) {
            float4 v = (lane < 28)
                ? ((const float4*)(aemb + 112*at))[lane]
                : ((const float4*)(remb + 112*rt))[lane - 28];
            o4[60 + lane] = v;
        }
    }
}

extern "C" void kernel_launch(void* const* d_in, const int* in_sizes, int n_in,
                              void* d_out, int out_size, void* d_ws, size_t ws_size,
                              hipStream_t stream)
{
    const float* coords = (const float*)d_in[0];
    const int*   at     = (const int*)  d_in[1];
    const int*   rt     = (const int*)  d_in[2];
    const float* tpw    = (const float*)d_in[3];
    const float* ae     = (const float*)d_in[4];
    const float* re     = (const float*)d_in[5];
    float* out = (float*)d_out;

    const int B = in_sizes[1] / NN;                  // 8
    float4* spts = (float4*)d_ws;
    int*    sids = (int*)(spts + (size_t)B * NN);
    float*  eHi  = (float*)(sids + (size_t)B * NN);
    float*  eLo  = eHi + (size_t)B * NN;

    bucket_kernel<<<B, 1024, 0, stream>>>(coords, spts, sids, eHi, eLo);
    protein_enc_kernel<<<B * (NN / QPB), BLOCK, 0, stream>>>(
        spts, sids, eHi, eLo, at, rt, tpw, ae, re, out);
}

// Round 20
// 120.047 us; speedup vs baseline: 1.8224x; 1.0472x over previous
//
#include <hip/hip_runtime.h>
#include <hip/hip_bf16.h>

#define NN    4096
#define KNEI  16
#define QPW   4              // query nodes per wave
#define WPB   8              // waves per block (512 threads)
#define BLOCK (WPB * 64)
#define QPB   (WPB * QPW)    // 32 queries per block
#define WIN   1600           // staged rank window (25 chunks of 64)
#define NCHF  25
#define NBKT  256
#define NEGB  -3.0e38f
#define PACKM 0xFFFFFFC0

typedef float f32x2 __attribute__((ext_vector_type(2)));
typedef int   i32x2 __attribute__((ext_vector_type(2)));

__device__ __forceinline__ int rlane(int v, int l)
{ return __builtin_amdgcn_readlane(v, l); }
__device__ __forceinline__ float rlanef(float v, int l)
{ return __int_as_float(__builtin_amdgcn_readlane(__float_as_int(v), l)); }

template<int CTRL>
__device__ __forceinline__ float rmax_step(float f)
{
    int s_ = __builtin_amdgcn_update_dpp(__float_as_int(f), __float_as_int(f),
                                         CTRL, 0xF, 0xF, false);
    return fmaxf(f, __int_as_float(s_));
}

template<int CTRL>
__device__ __forceinline__ void amax_step(float& f, int& i)
{
    int fs = __builtin_amdgcn_update_dpp(__float_as_int(f), __float_as_int(f),
                                         CTRL, 0xF, 0xF, false);
    int is = __builtin_amdgcn_update_dpp(i, i, CTRL, 0xF, 0xF, false);
    float ff = __int_as_float(fs);
    bool gt = ff > f;
    f = gt ? ff : f;
    i = gt ? is : i;
}

__device__ __forceinline__ void wave_amax(float f, int i, float& M, int& mi)
{
    amax_step<0x111>(f, i); amax_step<0x112>(f, i); amax_step<0x114>(f, i);
    amax_step<0x118>(f, i); amax_step<0x142>(f, i); amax_step<0x143>(f, i);
    M  = rlanef(f, 63);
    mi = rlane(i, 63);
}

__device__ __forceinline__ float row16_sum_dpp(float v)  // lane 16r+15 -> row sum
{
    float f = v;
#define STEPA(CTRL)                                                          \
    { int s_ = __builtin_amdgcn_update_dpp(0, __float_as_int(f),             \
               (CTRL), 0xF, 0xF, true);                                      \
      f += __int_as_float(s_); }
    STEPA(0x111) STEPA(0x112) STEPA(0x114) STEPA(0x118)
#undef STEPA
    return f;
}

__device__ __forceinline__ float bpermf(int abyte, float v)
{ return __int_as_float(__builtin_amdgcn_ds_bpermute(abyte, __float_as_int(v))); }

__device__ __forceinline__ float sel4f(float a, float b, float c, float d, int q)
{
    float lo = (q & 1) ? b : a;
    float hi = (q & 1) ? d : c;
    return (q & 2) ? hi : lo;
}

// purge self (always its scan-lane's packed max, possibly packed 2nd)
#define SELFFIX(bq, sq_, soff)                                               \
    {  int cb_ = __float_as_int(bq) & 63;                                    \
       if ((((cb_) << 6) | (lane ^ cb_)) == (soff)) { (bq) = (sq_); (sq_) = NEGB; } \
       int cs_ = __float_as_int(sq_) & 63;                                   \
       if ((((cs_) << 6) | (lane ^ cs_)) == (soff)) { (sq_) = NEGB; } }

// ---------------- hot windowed scan (LDS window, 25 chunks) ----------------
__device__ __forceinline__ void knn_scan_win(
    const float4* __restrict__ win, int blo, int rq0,
    float x0, float y0, float z0, float x1, float y1, float z1,
    float x2, float y2, float z2, float x3, float y3, float z3,
    int lane, int q, int gt, int* __restrict__ selw, float& f15)
{
    const f32x2 qAx = {x0, x1}, qAy = {y0, y1}, qAz = {z0, z1};
    const f32x2 qBx = {x2, x3}, qBy = {y2, y3}, qBz = {z2, z3};
    const i32x2 M2v = {(int)PACKM, (int)PACKM};

    f32x2 bA = {NEGB, NEGB}, sA = {NEGB, NEGB};
    f32x2 bB = {NEGB, NEGB}, sB = {NEGB, NEGB};

    #pragma unroll
    for (int c = 0; c < NCHF; ++c) {
        int off = (c << 6) | (lane ^ c);
        float4 P = win[off];
        f32x2 vx = {P.x, P.x}, vy = {P.y, P.y}, vz = {P.z, P.z}, vw = {P.w, P.w};
        f32x2 dA = __builtin_elementwise_fma(vx, qAx,
                   __builtin_elementwise_fma(vy, qAy,
                   __builtin_elementwise_fma(vz, qAz, vw)));
        f32x2 dB = __builtin_elementwise_fma(vx, qBx,
                   __builtin_elementwise_fma(vy, qBy,
                   __builtin_elementwise_fma(vz, qBz, vw)));
        i32x2 cc = {c, c};
        f32x2 pA = __builtin_bit_cast(f32x2,
                     (__builtin_bit_cast(i32x2, dA) & M2v) | cc);
        f32x2 pB = __builtin_bit_cast(f32x2,
                     (__builtin_bit_cast(i32x2, dB) & M2v) | cc);
        sA = __builtin_elementwise_max(sA, __builtin_elementwise_min(pA, bA));
        bA = __builtin_elementwise_max(bA, pA);
        sB = __builtin_elementwise_max(sB, __builtin_elementwise_min(pB, bB));
        bB = __builtin_elementwise_max(bB, pB);
    }

    float b0 = bA.x, b1 = bA.y, b2 = bB.x, b3 = bB.y;
    float s0 = sA.x, s1 = sA.y, s2 = sB.x, s3 = sB.y;

    const int sq0 = rq0 - blo;
    SELFFIX(b0, s0, sq0)
    SELFFIX(b1, s1, sq0 + 1)
    SELFFIX(b2, s2, sq0 + 2)
    SELFFIX(b3, s3, sq0 + 3)

    float pb0, pb1, pb2, pb3, ps0, ps1, ps2, ps3;
    {
        const int ab = gt << 2;
#define PULL(K, PB, PS)                                                      \
        {   int a = ab + ((K) << 6);                                         \
            PB = sel4f(bpermf(a,b0), bpermf(a,b1), bpermf(a,b2), bpermf(a,b3), q); \
            PS = sel4f(bpermf(a,s0), bpermf(a,s1), bpermf(a,s2), bpermf(a,s3), q); \
        }
        PULL(0, pb0, ps0)
        PULL(1, pb1, ps1)
        PULL(2, pb2, ps2)
        PULL(3, pb3, ps3)
#undef PULL
    }

#define REPLAYW(qq, xq, yq, zq)                                              \
    {   int wq = __ffsll(ex & (0xFFFFull << ((qq) * 16))) - 1;               \
        int colq = rlane(col, wq);                                           \
        int kq   = rlane(kf,  wq);                                           \
        float sf = NEGB;                                                     \
        int off2 = (lane << 6) | (colq ^ lane);                              \
        if (lane < NCHF) {                                                   \
            float4 Pp = win[off2];                                           \
            float scr = fmaf(Pp.x,(xq), fmaf(Pp.y,(yq), fmaf(Pp.z,(zq), Pp.w))); \
            sf = __int_as_float((__float_as_int(scr) & PACKM) | lane);       \
            int j2 = blo + off2;                                             \
            if (j2 == rq0 + (qq)) sf = NEGB;                                 \
            const int4* sp = (const int4*)&selw[(qq) << 4];                  \
            int4 sa = sp[0], sb = sp[1], sc = sp[2], sd = sp[3];             \
            if (j2==sa.x || j2==sa.y || j2==sa.z || j2==sa.w) sf = NEGB;     \
            if (j2==sb.x || j2==sb.y || j2==sb.z || j2==sb.w) sf = NEGB;     \
            if (j2==sc.x || j2==sc.y || j2==sc.z || j2==sc.w) sf = NEGB;     \
            if (j2==sd.x || j2==sd.y || j2==sd.z || j2==sd.w) sf = NEGB;     \
        }                                                                    \
        float M1; int i1;                                                    \
        wave_amax(sf, lane, M1, i1);                                         \
        float sf2 = (lane == i1) ? NEGB : sf;                                \
        float M2; int i2;                                                    \
        wave_amax(sf2, lane, M2, i2);                                        \
        bool ow = (lane == (qq) * 16 + (colq & 15));                         \
        if (kq == 0)      { pb0 = ow ? M1 : pb0; ps0 = ow ? M2 : ps0; }      \
        else if (kq == 1) { pb1 = ow ? M1 : pb1; ps1 = ow ? M2 : ps1; }      \
        else if (kq == 2) { pb2 = ow ? M1 : pb2; ps2 = ow ? M2 : ps2; }      \
        else              { pb3 = ow ? M1 : pb3; ps3 = ow ? M2 : ps3; }      \
    }

    const unsigned long long gmask = 0xFFFFull << (q << 4);
    #pragma unroll 1
    for (int r = 0; r < KNEI; ++r) {
        float f = fmaxf(fmaxf(pb0, pb1), fmaxf(pb2, pb3));
        f = rmax_step<0x121>(f); f = rmax_step<0x122>(f);
        f = rmax_step<0x124>(f); f = rmax_step<0x128>(f);
        bool c0 = (pb0 == f), c1 = (pb1 == f), c2 = (pb2 == f), c3 = (pb3 == f);
        unsigned long long m = __ballot(c0 | c1 | c2 | c3);
        int w = __ffsll(m & gmask) - 1;
        bool iwin = (lane == w);
        int kf = c0 ? 0 : (c1 ? 1 : (c2 ? 2 : 3));
        bool o0 = iwin && c0;
        bool o1 = iwin && !c0 && c1;
        bool o2 = iwin && !c0 && !c1 && c2;
        bool o3 = iwin && !c0 && !c1 && !c2;
        int cw  = __float_as_int(f) & 63;
        int col = gt + (kf << 4);
        int jw  = blo + ((cw << 6) | (col ^ cw));
        if (iwin) selw[(q << 4) + r] = jw;
        if (r == KNEI - 1) f15 = f;
        float pskf = o1 ? ps1 : (o2 ? ps2 : (o3 ? ps3 : ps0));
        bool e = iwin && (pskf == NEGB);
        pb0 = o0 ? ps0 : pb0;  ps0 = o0 ? NEGB : ps0;
        pb1 = o1 ? ps1 : pb1;  ps1 = o1 ? NEGB : ps1;
        pb2 = o2 ? ps2 : pb2;  ps2 = o2 ? NEGB : ps2;
        pb3 = o3 ? ps3 : pb3;  ps3 = o3 ? NEGB : ps3;
        unsigned long long ex = __ballot(e);
        if (ex) {
            if ((ex >>  0) & 0xFFFFull) REPLAYW(0, x0, y0, z0)
            if ((ex >> 16) & 0xFFFFull) REPLAYW(1, x1, y1, z1)
            if ((ex >> 32) & 0xFFFFull) REPLAYW(2, x2, y2, z2)
            if ((ex >> 48) & 0xFFFFull) REPLAYW(3, x3, y3, z3)
        }
    }
#undef REPLAYW
}

// ------------- cold exact full scan (global, noinline-isolated) -------------
__device__ __attribute__((noinline)) void knn_scan_full(
    const float4* __restrict__ gsb, int rq0,
    float x0, float y0, float z0, float x1, float y1, float z1,
    float x2, float y2, float z2, float x3, float y3, float z3,
    int lane, int q, int gt, int* __restrict__ selw)
{
    const f32x2 qAx = {x0, x1}, qAy = {y0, y1}, qAz = {z0, z1};
    const f32x2 qBx = {x2, x3}, qBy = {y2, y3}, qBz = {z2, z3};
    const i32x2 M2v = {(int)PACKM, (int)PACKM};

    f32x2 bA = {NEGB, NEGB}, sA = {NEGB, NEGB};
    f32x2 bB = {NEGB, NEGB}, sB = {NEGB, NEGB};

    #pragma unroll 4
    for (int c = 0; c < 64; ++c) {
        int off = (c << 6) | (lane ^ c);
        float4 P = gsb[off];
        f32x2 vx = {P.x, P.x}, vy = {P.y, P.y}, vz = {P.z, P.z}, vw = {P.w, P.w};
        f32x2 dA = __builtin_elementwise_fma(vx, qAx,
                   __builtin_elementwise_fma(vy, qAy,
                   __builtin_elementwise_fma(vz, qAz, vw)));
        f32x2 dB = __builtin_elementwise_fma(vx, qBx,
                   __builtin_elementwise_fma(vy, qBy,
                   __builtin_elementwise_fma(vz, qBz, vw)));
        i32x2 cc = {c, c};
        f32x2 pA = __builtin_bit_cast(f32x2,
                     (__builtin_bit_cast(i32x2, dA) & M2v) | cc);
        f32x2 pB = __builtin_bit_cast(f32x2,
                     (__builtin_bit_cast(i32x2, dB) & M2v) | cc);
        sA = __builtin_elementwise_max(sA, __builtin_elementwise_min(pA, bA));
        bA = __builtin_elementwise_max(bA, pA);
        sB = __builtin_elementwise_max(sB, __builtin_elementwise_min(pB, bB));
        bB = __builtin_elementwise_max(bB, pB);
    }

    float b0 = bA.x, b1 = bA.y, b2 = bB.x, b3 = bB.y;
    float s0 = sA.x, s1 = sA.y, s2 = sB.x, s3 = sB.y;

    SELFFIX(b0, s0, rq0)
    SELFFIX(b1, s1, rq0 + 1)
    SELFFIX(b2, s2, rq0 + 2)
    SELFFIX(b3, s3, rq0 + 3)

    float pb0, pb1, pb2, pb3, ps0, ps1, ps2, ps3;
    {
        const int ab = gt << 2;
#define PULL(K, PB, PS)                                                      \
        {   int a = ab + ((K) << 6);                                         \
            PB = sel4f(bpermf(a,b0), bpermf(a,b1), bpermf(a,b2), bpermf(a,b3), q); \
            PS = sel4f(bpermf(a,s0), bpermf(a,s1), bpermf(a,s2), bpermf(a,s3), q); \
        }
        PULL(0, pb0, ps0)
        PULL(1, pb1, ps1)
        PULL(2, pb2, ps2)
        PULL(3, pb3, ps3)
#undef PULL
    }

#define REPLAYF(qq, xq, yq, zq)                                              \
    {   int wq = __ffsll(ex & (0xFFFFull << ((qq) * 16))) - 1;               \
        int colq = rlane(col, wq);                                           \
        int kq   = rlane(kf,  wq);                                           \
        int j2 = (lane << 6) | (colq ^ lane);                                \
        float4 Pp = gsb[j2];                                                 \
        float scr = fmaf(Pp.x,(xq), fmaf(Pp.y,(yq), fmaf(Pp.z,(zq), Pp.w))); \
        float sf = __int_as_float((__float_as_int(scr) & PACKM) | lane);     \
        if (j2 == rq0 + (qq)) sf = NEGB;                                     \
        const int4* sp = (const int4*)&selw[(qq) << 4];                      \
        int4 sa = sp[0], sb = sp[1], sc = sp[2], sd = sp[3];                 \
        if (j2==sa.x || j2==sa.y || j2==sa.z || j2==sa.w) sf = NEGB;         \
        if (j2==sb.x || j2==sb.y || j2==sb.z || j2==sb.w) sf = NEGB;         \
        if (j2==sc.x || j2==sc.y || j2==sc.z || j2==sc.w) sf = NEGB;         \
        if (j2==sd.x || j2==sd.y || j2==sd.z || j2==sd.w) sf = NEGB;         \
        float M1; int i1;                                                    \
        wave_amax(sf, lane, M1, i1);                                         \
        float sf2 = (lane == i1) ? NEGB : sf;                                \
        float M2; int i2;                                                    \
        wave_amax(sf2, lane, M2, i2);                                        \
        bool ow = (lane == (qq) * 16 + (colq & 15));                         \
        if (kq == 0)      { pb0 = ow ? M1 : pb0; ps0 = ow ? M2 : ps0; }      \
        else if (kq == 1) { pb1 = ow ? M1 : pb1; ps1 = ow ? M2 : ps1; }      \
        else if (kq == 2) { pb2 = ow ? M1 : pb2; ps2 = ow ? M2 : ps2; }      \
        else              { pb3 = ow ? M1 : pb3; ps3 = ow ? M2 : ps3; }      \
    }

    const unsigned long long gmask = 0xFFFFull << (q << 4);
    #pragma unroll 1
    for (int r = 0; r < KNEI; ++r) {
        float f = fmaxf(fmaxf(pb0, pb1), fmaxf(pb2, pb3));
        f = rmax_step<0x121>(f); f = rmax_step<0x122>(f);
        f = rmax_step<0x124>(f); f = rmax_step<0x128>(f);
        bool c0 = (pb0 == f), c1 = (pb1 == f), c2 = (pb2 == f), c3 = (pb3 == f);
        unsigned long long m = __ballot(c0 | c1 | c2 | c3);
        int w = __ffsll(m & gmask) - 1;
        bool iwin = (lane == w);
        int kf = c0 ? 0 : (c1 ? 1 : (c2 ? 2 : 3));
        bool o0 = iwin && c0;
        bool o1 = iwin && !c0 && c1;
        bool o2 = iwin && !c0 && !c1 && c2;
        bool o3 = iwin && !c0 && !c1 && !c2;
        int cw  = __float_as_int(f) & 63;
        int col = gt + (kf << 4);
        int jw  = (cw << 6) | (col ^ cw);
        if (iwin) selw[(q << 4) + r] = jw;
        float pskf = o1 ? ps1 : (o2 ? ps2 : (o3 ? ps3 : ps0));
        bool e = iwin && (pskf == NEGB);
        pb0 = o0 ? ps0 : pb0;  ps0 = o0 ? NEGB : ps0;
        pb1 = o1 ? ps1 : pb1;  ps1 = o1 ? NEGB : ps1;
        pb2 = o2 ? ps2 : pb2;  ps2 = o2 ? NEGB : ps2;
        pb3 = o3 ? ps3 : pb3;  ps3 = o3 ? NEGB : ps3;
        unsigned long long ex = __ballot(e);
        if (ex) {
            if ((ex >>  0) & 0xFFFFull) REPLAYF(0, x0, y0, z0)
            if ((ex >> 16) & 0xFFFFull) REPLAYF(1, x1, y1, z1)
            if ((ex >> 32) & 0xFFFFull) REPLAYF(2, x2, y2, z2)
            if ((ex >> 48) & 0xFFFFull) REPLAYF(3, x3, y3, z3)
        }
    }
#undef REPLAYF
}

// ---- per-batch counting sort by x into 256 buckets (exact neighbor sets) ----
__global__ __launch_bounds__(1024)
void bucket_kernel(const float* __restrict__ coords,
                   float4* __restrict__ spts, int* __restrict__ sids,
                   float* __restrict__ eHi, float* __restrict__ eLo)
{
    __shared__ float sx[NN];
    __shared__ int   hist[NBKT + 1];
    __shared__ float rmin[16], rmax[16];

    const int b = blockIdx.x;
    const int t = threadIdx.x;
    const int lane = t & 63;
    const int wvv  = t >> 6;
    const float* cb = coords + (size_t)b * NN * 3;

    float lmin = 3.0e38f, lmax = -3.0e38f;
    for (int i = t; i < NN; i += 1024) {
        float x = cb[3*i];
        sx[i] = x;
        lmin = fminf(lmin, x);
        lmax = fmaxf(lmax, x);
    }
    #pragma unroll
    for (int o = 32; o >= 1; o >>= 1) {
        lmin = fminf(lmin, __shfl_xor(lmin, o));
        lmax = fmaxf(lmax, __shfl_xor(lmax, o));
    }
    if (lane == 0) { rmin[wvv] = lmin; rmax[wvv] = lmax; }
    if (t <= NBKT) hist[t] = 0;
    __syncthreads();
    if (t == 0) {
        float a = rmin[0], c = rmax[0];
        for (int k = 1; k < 16; ++k) { a = fminf(a, rmin[k]); c = fmaxf(c, rmax[k]); }
        rmin[0] = a; rmax[0] = c;
    }
    __syncthreads();
    const float xmin = rmin[0];
    const float bw   = fmaxf((rmax[0] - xmin) * (1.0f / NBKT), 1e-6f);
    const float ibw  = 1.0f / bw;

    for (int i = t; i < NN; i += 1024) {
        int bk = (int)((sx[i] - xmin) * ibw);
        bk = min(NBKT - 1, max(0, bk));
        atomicAdd(&hist[bk + 1], 1);
    }
    __syncthreads();
    if (t == 0) {
        int acc = 0;
        for (int k = 0; k <= NBKT; ++k) { acc += hist[k]; hist[k] = acc; }
    }
    __syncthreads();
    for (int i = t; i < NN; i += 1024) {
        float x = sx[i];
        int bk = (int)((x - xmin) * ibw);
        bk = min(NBKT - 1, max(0, bk));
        int pos = atomicAdd(&hist[bk], 1);
        float y = cb[3*i + 1], z = cb[3*i + 2];
        size_t o = (size_t)b * NN + pos;
        spts[o] = make_float4(x, y, z, -0.5f * (x*x + y*y + z*z));
        sids[o] = i;
        eHi[o] = xmin + (bk + 1) * bw;
        eLo[o] = xmin + bk * bw;
    }
}

__global__ __launch_bounds__(BLOCK, 8)
void protein_enc_kernel(const float4* __restrict__ spts,
                        const int*   __restrict__ sids,
                        const float* __restrict__ eHi,
                        const float* __restrict__ eLo,
                        const int*   __restrict__ atypes,
                        const int*   __restrict__ rtypes,
                        const float* __restrict__ tpw,
                        const float* __restrict__ aemb,
                        const float* __restrict__ remb,
                        float* __restrict__ out)
{
    __shared__ float4 win[WIN];         // 25.6 KB rank window
    __shared__ float  sW[8 * 32];
    __shared__ int    sel[WPB * 64];    // absolute ranks

    const int tid  = threadIdx.x;
    const int lane = tid & 63;
    const int wv   = tid >> 6;
    const int bpb  = NN / QPB;          // 128
    const int batch    = blockIdx.x / bpb;
    const int nodeBase = (blockIdx.x % bpb) * QPB;

    const float4* gsb = spts + (size_t)batch * NN;

    int blo = nodeBase - 784;            // center 1600-window on queries
    if (blo < 0) blo = 0;
    blo &= ~63;
    if (blo > NN - WIN) blo = NN - WIN;  // 2496 (64-aligned)

    for (int t = tid; t < WIN; t += BLOCK) win[t] = gsb[blo + t];
    if (tid < 256) sW[tid] = tpw[tid];
    sel[tid] = -1;
    __syncthreads();

    const int rq0 = nodeBase + wv * QPW;
    const float4 Q0 = win[rq0 - blo],   Q1 = win[rq0+1 - blo];
    const float4 Q2 = win[rq0+2 - blo], Q3 = win[rq0+3 - blo];
    const float x0 = Q0.x, y0 = Q0.y, z0 = Q0.z;
    const float x1 = Q1.x, y1 = Q1.y, z1 = Q1.z;
    const float x2 = Q2.x, y2 = Q2.y, z2 = Q2.z;
    const float x3 = Q3.x, y3 = Q3.y, z3 = Q3.z;

    const int q  = lane >> 4;
    const int gt = lane & 15;
    int* selw = &sel[wv * 64];

    float f15 = NEGB;
    knn_scan_win(win, blo, rq0, x0,y0,z0, x1,y1,z1, x2,y2,z2, x3,y3,z3,
                 lane, q, gt, selw, f15);

    float xq = (q & 2) ? ((q & 1) ? x3 : x2) : ((q & 1) ? x1 : x0);
    float yq = (q & 2) ? ((q & 1) ? y3 : y2) : ((q & 1) ? y1 : y0);
    float zq = (q & 2) ? ((q & 1) ? z3 : z2) : ((q & 1) ? z1 : z0);

    // ---- exactness: bucket-edge bounds must dominate d2_16 ----
    bool didFull = false;
    {
        float n2q = xq*xq + yq*yq + zq*zq;
        float d2safe = fmaf(-2.0f, f15, n2q) + 0.125f;
        bool lok = (blo == 0);
        if (!lok) {
            float xloB = eHi[(size_t)batch * NN + blo - 1];
            float dl = xq - xloB;
            lok = (dl > 0.0f) && (dl * dl >= d2safe);
        }
        bool rok = (blo + WIN >= NN);
        if (!rok) {
            float xhiB = eLo[(size_t)batch * NN + blo + WIN];
            float dr = xhiB - xq;
            rok = (dr > 0.0f) && (dr * dr >= d2safe);
        }
        unsigned long long fb = __ballot(!(lok && rok));
        if (fb) {                        // rare now: exact full rescan
            selw[lane] = -1;
            knn_scan_full(gsb, rq0, x0,y0,z0, x1,y1,z1, x2,y2,z2, x3,y3,z3,
                          lane, q, gt, selw);
            didFull = true;
        }
    }

    // ---- epilogue: lane (16q+gt) owns edge gt of query q ----
    int selIdx = selw[lane];
    float4 P = didFull ? gsb[selIdx] : win[selIdx - blo];
    float rx = P.x - xq, ry = P.y - yq, rz = P.z - zq;
    float dist = sqrtf(rx*rx + ry*ry + rz*rz);
    float inv  = 1.0f / (dist + 1e-8f);
    float hx = rx * inv, hy = ry * inv, hz = rz * inv;
    float cu = fminf(dist / 10.0f, 1.0f);
    float A = expf(cu * cu * -32.0f);
    float E = expf(cu * (64.0f / 7.0f));
    const float K[8] = {1.0f, 0.5204501f, 0.0733697f, 0.00280164f,
                        2.897772e-05f, 8.11857e-08f, 6.16130e-11f,
                        1.2664166e-14f};
    float gg[8];
    float t = A, ssum = A;
    gg[0] = A;
    #pragma unroll
    for (int v = 1; v < 8; ++v) { t *= E; gg[v] = t * K[v]; ssum += gg[v]; }
    float is = 1.0f / ssum;
    float S[24];
    #pragma unroll
    for (int v = 0; v < 8; ++v) {
        float rbv = gg[v] * is;
        S[3*v]   = rbv * hx;
        S[3*v+1] = rbv * hy;
        S[3*v+2] = rbv * hz;
    }
    #pragma unroll
    for (int t2 = 0; t2 < 24; ++t2) S[t2] = row16_sum_dpp(S[t2]);

    float wcol[8];
    #pragma unroll
    for (int v = 0; v < 8; ++v) wcol[v] = sW[32*v + (lane & 31)];

    const float scale = 0.036084391824351613f;   // 1/(16*sqrt(3))
    const float4 z4 = make_float4(0.f, 0.f, 0.f, 0.f);

    #pragma unroll
    for (int qq = 0; qq < QPW; ++qq) {
        const int gid = sids[(size_t)batch * NN + rq0 + qq];
        const int gq  = batch * NN + gid;
        float sg[24];
        #pragma unroll
        for (int t2 = 0; t2 < 24; ++t2) sg[t2] = rlanef(S[t2], 16 * qq + 15);

        float* onode = out + (size_t)gq * 464;
        float4* o4 = (float4*)onode;
        if (lane < 16)       o4[lane] = z4;          // ch 0..63
        else if (lane < 36)  o4[lane + 24] = z4;     // ch 160..239

        if (lane < 32) {
            float a0 = 0.f, a1 = 0.f, a2 = 0.f;
            #pragma unroll
            for (int v = 0; v < 8; ++v) {
                a0 = fmaf(wcol[v], sg[3*v],   a0);
                a1 = fmaf(wcol[v], sg[3*v+1], a1);
                a2 = fmaf(wcol[v], sg[3*v+2], a2);
            }
            onode[64 + 3*lane]     = a0 * scale;
            onode[64 + 3*lane + 1] = a1 * scale;
            onode[64 + 3*lane + 2] = a2 * scale;
        }

        const int at = atypes[gq];
        const int rt = rtypes[gq];
        if (lane < 56) {
            float4 v = (lane < 28)
                ? ((const float4*)(aemb + 112*at))[lane]
                : ((const float4*)(remb + 112*rt))[lane - 28];
            o4[60 + lane] = v;
        }
    }
}

extern "C" void kernel_launch(void* const* d_in, const int* in_sizes, int n_in,
                              void* d_out, int out_size, void* d_ws, size_t ws_size,
                              hipStream_t stream)
{
    const float* coords = (const float*)d_in[0];
    const int*   at     = (const int*)  d_in[1];
    const int*   rt     = (const int*)  d_in[2];
    const float* tpw    = (const float*)d_in[3];
    const float* ae     = (const float*)d_in[4];
    const float* re     = (const float*)d_in[5];
    float* out = (float*)d_out;

    const int B = in_sizes[1] / NN;                  // 8
    float4* spts = (float4*)d_ws;
    int*    sids = (int*)(spts + (size_t)B * NN);
    float*  eHi  = (float*)(sids + (size_t)B * NN);
    float*  eLo  = eHi + (size_t)B * NN;

    bucket_kernel<<<B, 1024, 0, stream>>>(coords, spts, sids, eHi, eLo);
    protein_enc_kernel<<<B * (NN / QPB), BLOCK, 0, stream>>>(
        spts, sids, eHi, eLo, at, rt, tpw, ae, re, out);
}

// Round 21
// 83.515 us; speedup vs baseline: 2.6196x; 1.4374x over previous
//
#include <hip/hip_runtime.h>
#include <hip/hip_bf16.h>

#define NN    4096
#define KNEI  16
#define QPW   4              // query nodes per wave
#define WPB   4              // waves per block (256 threads)
#define BLOCK (WPB * 64)
#define QPB   (WPB * QPW)    // 16 queries per block
#define NEGB  -3.0e38f
#define PACKM 0xFFFFFFC0

typedef float f32x2 __attribute__((ext_vector_type(2)));
typedef int   i32x2 __attribute__((ext_vector_type(2)));

__device__ __forceinline__ int rlane(int v, int l)
{ return __builtin_amdgcn_readlane(v, l); }
__device__ __forceinline__ float rlanef(float v, int l)
{ return __int_as_float(__builtin_amdgcn_readlane(__float_as_int(v), l)); }

// f-only DPP max step (row_ror rotate-reduce)
template<int CTRL>
__device__ __forceinline__ float rmax_step(float f)
{
    int s_ = __builtin_amdgcn_update_dpp(__float_as_int(f), __float_as_int(f),
                                         CTRL, 0xF, 0xF, false);
    return fmaxf(f, __int_as_float(s_));
}

// (f,i) joint argmax step — replay path only
template<int CTRL>
__device__ __forceinline__ void amax_step(float& f, int& i)
{
    int fs = __builtin_amdgcn_update_dpp(__float_as_int(f), __float_as_int(f),
                                         CTRL, 0xF, 0xF, false);
    int is = __builtin_amdgcn_update_dpp(i, i, CTRL, 0xF, 0xF, false);
    float ff = __int_as_float(fs);
    bool gt = ff > f;
    f = gt ? ff : f;
    i = gt ? is : i;
}

__device__ __forceinline__ void wave_amax(float f, int i, float& M, int& mi)
{
    amax_step<0x111>(f, i); amax_step<0x112>(f, i); amax_step<0x114>(f, i);
    amax_step<0x118>(f, i); amax_step<0x142>(f, i); amax_step<0x143>(f, i);
    M  = rlanef(f, 63);
    mi = rlane(i, 63);
}

__device__ __forceinline__ float row16_sum_dpp(float v)  // lane 16r+15 -> row sum
{
    float f = v;
#define STEPA(CTRL)                                                          \
    { int s_ = __builtin_amdgcn_update_dpp(0, __float_as_int(f),             \
               (CTRL), 0xF, 0xF, true);                                      \
      f += __int_as_float(s_); }
    STEPA(0x111) STEPA(0x112) STEPA(0x114) STEPA(0x118)
#undef STEPA
    return f;
}

__device__ __forceinline__ float bpermf(int abyte, float v)
{ return __int_as_float(__builtin_amdgcn_ds_bpermute(abyte, __float_as_int(v))); }

__device__ __forceinline__ float sel4f(float a, float b, float c, float d, int q)
{
    float lo = (q & 1) ? b : a;
    float hi = (q & 1) ? d : c;
    return (q & 2) ? hi : lo;
}

// purge self (always its column's packed max, possibly packed 2nd)
#define SELFFIX(q, b, s)                                                     \
    {  int cb_ = __float_as_int(b) & 63;                                     \
       if ((((cb_) << 6) | (lane ^ cb_)) == q0 + (q)) { (b) = (s); (s) = NEGB; } \
       int cs_ = __float_as_int(s) & 63;                                     \
       if ((((cs_) << 6) | (lane ^ cs_)) == q0 + (q)) { (s) = NEGB; } }

// rare wave-wide replay: rebuild column colq's top-2 unselected members
#define REPLAY(qq, xq, yq, zq)                                               \
    {   int wq = __ffsll(ex & (0xFFFFull << ((qq) * 16))) - 1;               \
        int colq = rlane(col, wq);                                           \
        int kq   = rlane(kf,  wq);                                           \
        int j2 = (lane << 6) | (colq ^ lane);                                \
        float4 Pp = gsb[j2];                                                 \
        float scr = fmaf(Pp.x,(xq), fmaf(Pp.y,(yq), fmaf(Pp.z,(zq), Pp.w))); \
        float sf = __int_as_float((__float_as_int(scr) & PACKM) | lane);     \
        if (j2 == q0 + (qq)) sf = NEGB;                                      \
        const int4* sp = (const int4*)&sel[wv * 64 + ((qq) << 4)];           \
        int4 sa = sp[0], sb = sp[1], sc = sp[2], sd = sp[3];                 \
        if (j2==sa.x || j2==sa.y || j2==sa.z || j2==sa.w) sf = NEGB;         \
        if (j2==sb.x || j2==sb.y || j2==sb.z || j2==sb.w) sf = NEGB;         \
        if (j2==sc.x || j2==sc.y || j2==sc.z || j2==sc.w) sf = NEGB;         \
        if (j2==sd.x || j2==sd.y || j2==sd.z || j2==sd.w) sf = NEGB;         \
        float M1; int i1;                                                    \
        wave_amax(sf, j2, M1, i1);                                           \
        float sf2 = (j2 == i1) ? NEGB : sf;                                  \
        float M2; int i2;                                                    \
        wave_amax(sf2, j2, M2, i2);                                          \
        bool ow = (lane == (qq) * 16 + (colq & 15));                         \
        if (kq == 0)      { pb0 = ow ? M1 : pb0; ps0 = ow ? M2 : ps0; }      \
        else if (kq == 1) { pb1 = ow ? M1 : pb1; ps1 = ow ? M2 : ps1; }      \
        else if (kq == 2) { pb2 = ow ? M1 : pb2; ps2 = ow ? M2 : ps2; }      \
        else              { pb3 = ow ? M1 : pb3; ps3 = ow ? M2 : ps3; }      \
    }

// ---- prep: spts[b*NN+p] = (x, y, z, -n2/2) — once, trivially parallel ----
__global__ __launch_bounds__(256)
void prep_kernel(const float* __restrict__ coords, float4* __restrict__ spts,
                 int total)
{
    int i = blockIdx.x * 256 + threadIdx.x;
    if (i < total) {
        float x = coords[3*i], y = coords[3*i+1], z = coords[3*i+2];
        spts[i] = make_float4(x, y, z, -0.5f * (x*x + y*y + z*z));
    }
}

__global__ __launch_bounds__(BLOCK, 8)
void protein_enc_kernel(const float4* __restrict__ spts,
                        const int*   __restrict__ atypes,
                        const int*   __restrict__ rtypes,
                        const float* __restrict__ tpw,
                        const float* __restrict__ aemb,
                        const float* __restrict__ remb,
                        float* __restrict__ out)
{
    __shared__ int sel[WPB * 64];       // 1 KB: [wave][q][r] selected indices

    const int tid  = threadIdx.x;
    const int lane = tid & 63;
    const int wv   = tid >> 6;
    const int bpb  = NN / QPB;          // 256
    const int batch    = blockIdx.x / bpb;
    const int nodeBase = (blockIdx.x % bpb) * QPB;

    const float4* gsb = spts + (size_t)batch * NN;
    sel[wv * 64 + lane] = -1;           // wave-private, no barrier needed

    const int q0 = nodeBase + wv * QPW;          // this wave's 4 query nodes
    const float4 P0 = gsb[q0],   P1 = gsb[q0+1];
    const float4 P2 = gsb[q0+2], P3 = gsb[q0+3];
    const float x0 = P0.x, y0 = P0.y, z0 = P0.z;
    const float x1 = P1.x, y1 = P1.y, z1 = P1.z;
    const float x2 = P2.x, y2 = P2.y, z2 = P2.z;
    const float x3 = P3.x, y3 = P3.y, z3 = P3.z;

    const f32x2 qAx = {x0, x1}, qAy = {y0, y1}, qAz = {z0, z1};
    const f32x2 qBx = {x2, x3}, qBy = {y2, y3}, qBz = {z2, z3};
    const i32x2 M2v = {(int)PACKM, (int)PACKM};

    // ---- phase 1: diagonal scan straight from L2; packed pk ladders ----
    f32x2 bA = {NEGB, NEGB}, sA = {NEGB, NEGB};
    f32x2 bB = {NEGB, NEGB}, sB = {NEGB, NEGB};

    #pragma unroll 8
    for (int c = 0; c < NN / 64; ++c) {
        int j = (c << 6) | (lane ^ c);
        float4 P = gsb[j];
        f32x2 vx = {P.x, P.x}, vy = {P.y, P.y}, vz = {P.z, P.z}, vw = {P.w, P.w};
        f32x2 dA = __builtin_elementwise_fma(vx, qAx,
                   __builtin_elementwise_fma(vy, qAy,
                   __builtin_elementwise_fma(vz, qAz, vw)));
        f32x2 dB = __builtin_elementwise_fma(vx, qBx,
                   __builtin_elementwise_fma(vy, qBy,
                   __builtin_elementwise_fma(vz, qBz, vw)));
        i32x2 cc = {c, c};
        f32x2 pA = __builtin_bit_cast(f32x2,
                     (__builtin_bit_cast(i32x2, dA) & M2v) | cc);
        f32x2 pB = __builtin_bit_cast(f32x2,
                     (__builtin_bit_cast(i32x2, dB) & M2v) | cc);
        sA = __builtin_elementwise_max(sA, __builtin_elementwise_min(pA, bA));
        bA = __builtin_elementwise_max(bA, pA);
        sB = __builtin_elementwise_max(sB, __builtin_elementwise_min(pB, bB));
        bB = __builtin_elementwise_max(bB, pB);
    }

    float b0 = bA.x, b1 = bA.y, b2 = bB.x, b3 = bB.y;
    float s0 = sA.x, s1 = sA.y, s2 = sB.x, s3 = sB.y;

    SELFFIX(0, b0, s0)
    SELFFIX(1, b1, s1)
    SELFFIX(2, b2, s2)
    SELFFIX(3, b3, s3)

    // ---- redistribute: query q -> lanes 16q..16q+15; lane t owns columns
    //      {t, t+16, t+32, t+48} as slots 0..3 ----
    const int q  = lane >> 4;
    const int gt = lane & 15;
    float pb0, pb1, pb2, pb3, ps0, ps1, ps2, ps3;
    {
        const int ab = gt << 2;     // byte addr of source lane (column id)
#define PULL(K, PB, PS)                                                      \
        {   int a = ab + ((K) << 6);                                         \
            PB = sel4f(bpermf(a,b0), bpermf(a,b1), bpermf(a,b2), bpermf(a,b3), q); \
            PS = sel4f(bpermf(a,s0), bpermf(a,s1), bpermf(a,s2), bpermf(a,s3), q); \
        }
        PULL(0, pb0, ps0)
        PULL(1, pb1, ps1)
        PULL(2, pb2, ps2)
        PULL(3, pb3, ps3)
#undef PULL
    }

    // ---- phase 2: 16 rounds; f-only row reduce + owner-claim ----
    const unsigned long long gmask = 0xFFFFull << (q << 4);
    const int selbase = wv * 64 + (q << 4);

    #pragma unroll 1
    for (int r = 0; r < KNEI; ++r) {
        float f = fmaxf(fmaxf(pb0, pb1), fmaxf(pb2, pb3));
        f = rmax_step<0x121>(f); f = rmax_step<0x122>(f);
        f = rmax_step<0x124>(f); f = rmax_step<0x128>(f);
        // owner claim: bit-exact match against the row max
        bool c0 = (pb0 == f), c1 = (pb1 == f), c2 = (pb2 == f), c3 = (pb3 == f);
        unsigned long long m = __ballot(c0 | c1 | c2 | c3);
        int w = __ffsll(m & gmask) - 1;
        bool iwin = (lane == w);
        int kf = c0 ? 0 : (c1 ? 1 : (c2 ? 2 : 3));       // priority slot
        bool o0 = iwin && c0;
        bool o1 = iwin && !c0 && c1;
        bool o2 = iwin && !c0 && !c1 && c2;
        bool o3 = iwin && !c0 && !c1 && !c2;
        int cw  = __float_as_int(f) & 63;                // winner's row
        int col = gt + (kf << 4);                        // valid at owner
        int jw  = (cw << 6) | (col ^ cw);
        if (iwin) sel[selbase + r] = jw;
        float pskf = o1 ? ps1 : (o2 ? ps2 : (o3 ? ps3 : ps0));
        bool e = iwin && (pskf == NEGB);
        pb0 = o0 ? ps0 : pb0;  ps0 = o0 ? NEGB : ps0;
        pb1 = o1 ? ps1 : pb1;  ps1 = o1 ? NEGB : ps1;
        pb2 = o2 ? ps2 : pb2;  ps2 = o2 ? NEGB : ps2;
        pb3 = o3 ? ps3 : pb3;  ps3 = o3 ? NEGB : ps3;
        unsigned long long ex = __ballot(e);
        if (ex) {                                 // rare refill path
            if ((ex >>  0) & 0xFFFFull) REPLAY(0, x0, y0, z0)
            if ((ex >> 16) & 0xFFFFull) REPLAY(1, x1, y1, z1)
            if ((ex >> 32) & 0xFFFFull) REPLAY(2, x2, y2, z2)
            if ((ex >> 48) & 0xFFFFull) REPLAY(3, x3, y3, z3)
        }
    }

    // ---- epilogue: lane (16q+gt) owns edge gt of query q ----
    int selIdx = sel[wv * 64 + lane];

    float xq = (q & 2) ? ((q & 1) ? x3 : x2) : ((q & 1) ? x1 : x0);
    float yq = (q & 2) ? ((q & 1) ? y3 : y2) : ((q & 1) ? y1 : y0);
    float zq = (q & 2) ? ((q & 1) ? z3 : z2) : ((q & 1) ? z1 : z0);

    float4 P = gsb[selIdx];
    float rx = P.x - xq, ry = P.y - yq, rz = P.z - zq;   // sender - receiver
    float dist = sqrtf(rx*rx + ry*ry + rz*rz);
    float inv  = 1.0f / (dist + 1e-8f);
    float hx = rx * inv, hy = ry * inv, hz = rz * inv;
    float cu = fminf(dist / 10.0f, 1.0f);
    // g[v] = exp(-32(cu - v/7)^2) = A * E^v * K[v];  2 expf instead of 8
    float A = expf(cu * cu * -32.0f);
    float E = expf(cu * (64.0f / 7.0f));
    const float K[8] = {1.0f, 0.5204501f, 0.0733697f, 0.00280164f,
                        2.897772e-05f, 8.11857e-08f, 6.16130e-11f,
                        1.2664166e-14f};
    float gg[8];
    float t = A, ssum = A;
    gg[0] = A;
    #pragma unroll
    for (int v = 1; v < 8; ++v) { t *= E; gg[v] = t * K[v]; ssum += gg[v]; }
    float is = 1.0f / ssum;
    float S[24];
    #pragma unroll
    for (int v = 0; v < 8; ++v) {
        float rbv = gg[v] * is;
        S[3*v]   = rbv * hx;
        S[3*v+1] = rbv * hy;
        S[3*v+2] = rbv * hz;
    }
    #pragma unroll
    for (int t2 = 0; t2 < 24; ++t2) S[t2] = row16_sum_dpp(S[t2]);

    // W column straight from global (L2-hit)
    float wcol[8];
    #pragma unroll
    for (int v = 0; v < 8; ++v) wcol[v] = tpw[32*v + (lane & 31)];

    const float scale = 0.036084391824351613f;   // 1/(16*sqrt(3))
    const float4 z4 = make_float4(0.f, 0.f, 0.f, 0.f);

    #pragma unroll
    for (int qq = 0; qq < QPW; ++qq) {
        const int gq = batch * NN + q0 + qq;
        float sg[24];
        #pragma unroll
        for (int t2 = 0; t2 < 24; ++t2) sg[t2] = rlanef(S[t2], 16 * qq + 15);

        float* onode = out + (size_t)gq * 464;
        float4* o4 = (float4*)onode;
        if (lane < 16)       o4[lane] = z4;          // ch 0..63
        else if (lane < 36)  o4[lane + 24] = z4;     // ch 160..239

        if (lane < 32) {
            float a0 = 0.f, a1 = 0.f, a2 = 0.f;
            #pragma unroll
            for (int v = 0; v < 8; ++v) {
                a0 = fmaf(wcol[v], sg[3*v],   a0);
                a1 = fmaf(wcol[v], sg[3*v+1], a1);
                a2 = fmaf(wcol[v], sg[3*v+2], a2);
            }
            onode[64 + 3*lane]     = a0 * scale;
            onode[64 + 3*lane + 1] = a1 * scale;
            onode[64 + 3*lane + 2] = a2 * scale;
        }

        const int at = atypes[gq];
        const int rt = rtypes[gq];
        if (lane < 56) {
            float4 v = (lane < 28)
                ? ((const float4*)(aemb + 112*at))[lane]
                : ((const float4*)(remb + 112*rt))[lane - 28];
            o4[60 + lane] = v;
        }
    }
}

extern "C" void kernel_launch(void* const* d_in, const int* in_sizes, int n_in,
                              void* d_out, int out_size, void* d_ws, size_t ws_size,
                              hipStream_t stream)
{
    const float* coords = (const float*)d_in[0];
    const int*   at     = (const int*)  d_in[1];
    const int*   rt     = (const int*)  d_in[2];
    const float* tpw    = (const float*)d_in[3];
    const float* ae     = (const float*)d_in[4];
    const float* re     = (const float*)d_in[5];
    float* out = (float*)d_out;

    const int B = in_sizes[1] / NN;                  // 8
    const int total = B * NN;
    float4* spts = (float4*)d_ws;

    prep_kernel<<<(total + 255) / 256, 256, 0, stream>>>(coords, spts, total);
    protein_enc_kernel<<<B * (NN / QPB), BLOCK, 0, stream>>>(
        spts, at, rt, tpw, ae, re, out);
}

// Round 22
// 72.919 us; speedup vs baseline: 3.0002x; 1.1453x over previous
//
#include <hip/hip_runtime.h>
#include <hip/hip_bf16.h>

#define NN    4096
#define KNEI  16
#define QPW   4              // query nodes per wave
#define WPB   16             // waves per block
#define BLOCK (WPB * 64)
#define QPB   (WPB * QPW)    // 64 queries per block
#define NEGB  -3.0e38f
#define PACKM 0xFFFFFFC0

typedef float f32x2 __attribute__((ext_vector_type(2)));
typedef int   i32x2 __attribute__((ext_vector_type(2)));

__device__ __forceinline__ int rlane(int v, int l)
{ return __builtin_amdgcn_readlane(v, l); }
__device__ __forceinline__ float rlanef(float v, int l)
{ return __int_as_float(__builtin_amdgcn_readlane(__float_as_int(v), l)); }

// f-only DPP max step (row_ror rotate-reduce)
template<int CTRL>
__device__ __forceinline__ float rmax_step(float f)
{
    int s_ = __builtin_amdgcn_update_dpp(__float_as_int(f), __float_as_int(f),
                                         CTRL, 0xF, 0xF, false);
    return fmaxf(f, __int_as_float(s_));
}

// (f,i) joint argmax step — replay path only
template<int CTRL>
__device__ __forceinline__ void amax_step(float& f, int& i)
{
    int fs = __builtin_amdgcn_update_dpp(__float_as_int(f), __float_as_int(f),
                                         CTRL, 0xF, 0xF, false);
    int is = __builtin_amdgcn_update_dpp(i, i, CTRL, 0xF, 0xF, false);
    float ff = __int_as_float(fs);
    bool gt = ff > f;
    f = gt ? ff : f;
    i = gt ? is : i;
}

__device__ __forceinline__ void wave_amax(float f, int i, float& M, int& mi)
{
    amax_step<0x111>(f, i); amax_step<0x112>(f, i); amax_step<0x114>(f, i);
    amax_step<0x118>(f, i); amax_step<0x142>(f, i); amax_step<0x143>(f, i);
    M  = rlanef(f, 63);
    mi = rlane(i, 63);
}

__device__ __forceinline__ float row16_sum_dpp(float v)  // lane 16r+15 -> row sum
{
    float f = v;
#define STEPA(CTRL)                                                          \
    { int s_ = __builtin_amdgcn_update_dpp(0, __float_as_int(f),             \
               (CTRL), 0xF, 0xF, true);                                      \
      f += __int_as_float(s_); }
    STEPA(0x111) STEPA(0x112) STEPA(0x114) STEPA(0x118)
#undef STEPA
    return f;
}

__device__ __forceinline__ float bpermf(int abyte, float v)
{ return __int_as_float(__builtin_amdgcn_ds_bpermute(abyte, __float_as_int(v))); }

__device__ __forceinline__ float sel4f(float a, float b, float c, float d, int q)
{
    float lo = (q & 1) ? b : a;
    float hi = (q & 1) ? d : c;
    return (q & 2) ? hi : lo;
}

// purge self (always its column's packed max, possibly packed 2nd)
#define SELFFIX(q, b, s)                                                     \
    {  int cb_ = __float_as_int(b) & 63;                                     \
       if ((((cb_) << 6) | (lane ^ cb_)) == q0 + (q)) { (b) = (s); (s) = NEGB; } \
       int cs_ = __float_as_int(s) & 63;                                     \
       if ((((cs_) << 6) | (lane ^ cs_)) == q0 + (q)) { (s) = NEGB; } }

// rare wave-wide replay: rebuild column colq's top-2 unselected members
#define REPLAY(qq, xq, yq, zq)                                               \
    {   int wq = __ffsll(ex & (0xFFFFull << ((qq) * 16))) - 1;               \
        int colq = rlane(col, wq);                                           \
        int kq   = rlane(kf,  wq);                                           \
        int j2 = (lane << 6) | (colq ^ lane);                                \
        float4 Pp = pts[j2];                                                 \
        float scr = fmaf(Pp.x,(xq), fmaf(Pp.y,(yq), fmaf(Pp.z,(zq), Pp.w))); \
        float sf = __int_as_float((__float_as_int(scr) & PACKM) | lane);     \
        if (j2 == q0 + (qq)) sf = NEGB;                                      \
        const int4* sp = (const int4*)&sel[wv * 64 + ((qq) << 4)];           \
        int4 sa = sp[0], sb = sp[1], sc = sp[2], sd = sp[3];                 \
        if (j2==sa.x || j2==sa.y || j2==sa.z || j2==sa.w) sf = NEGB;         \
        if (j2==sb.x || j2==sb.y || j2==sb.z || j2==sb.w) sf = NEGB;         \
        if (j2==sc.x || j2==sc.y || j2==sc.z || j2==sc.w) sf = NEGB;         \
        if (j2==sd.x || j2==sd.y || j2==sd.z || j2==sd.w) sf = NEGB;         \
        float M1; int i1;                                                    \
        wave_amax(sf, j2, M1, i1);                                           \
        float sf2 = (j2 == i1) ? NEGB : sf;                                  \
        float M2; int i2;                                                    \
        wave_amax(sf2, j2, M2, i2);                                          \
        bool ow = (lane == (qq) * 16 + (colq & 15));                         \
        if (kq == 0)      { pb0 = ow ? M1 : pb0; ps0 = ow ? M2 : ps0; }      \
        else if (kq == 1) { pb1 = ow ? M1 : pb1; ps1 = ow ? M2 : ps1; }      \
        else if (kq == 2) { pb2 = ow ? M1 : pb2; ps2 = ow ? M2 : ps2; }      \
        else              { pb3 = ow ? M1 : pb3; ps3 = ow ? M2 : ps3; }      \
    }

// 4 loads of diagonal candidates into a register buffer (constant-indexed)
#define LOAD4(BUF, CG)                                                       \
    _Pragma("unroll")                                                        \
    for (int u = 0; u < 4; ++u) {                                            \
        int c_ = (CG) * 4 + u;                                               \
        BUF[u] = pts[(c_ << 6) | (lane ^ c_)];                               \
    }

// 4 compute steps: packed scores + pk top-2 ladders for 4 queries
#define COMP4(BUF, CG)                                                       \
    _Pragma("unroll")                                                        \
    for (int u = 0; u < 4; ++u) {                                            \
        int c_ = (CG) * 4 + u;                                               \
        float4 P = BUF[u];                                                   \
        f32x2 vx = {P.x, P.x}, vy = {P.y, P.y};                              \
        f32x2 vz = {P.z, P.z}, vw = {P.w, P.w};                              \
        f32x2 dA = __builtin_elementwise_fma(vx, qAx,                        \
                   __builtin_elementwise_fma(vy, qAy,                        \
                   __builtin_elementwise_fma(vz, qAz, vw)));                 \
        f32x2 dB = __builtin_elementwise_fma(vx, qBx,                        \
                   __builtin_elementwise_fma(vy, qBy,                        \
                   __builtin_elementwise_fma(vz, qBz, vw)));                 \
        i32x2 cc = {c_, c_};                                                 \
        f32x2 pA = __builtin_bit_cast(f32x2,                                 \
                     (__builtin_bit_cast(i32x2, dA) & M2v) | cc);            \
        f32x2 pB = __builtin_bit_cast(f32x2,                                 \
                     (__builtin_bit_cast(i32x2, dB) & M2v) | cc);            \
        sA = __builtin_elementwise_max(sA, __builtin_elementwise_min(pA, bA)); \
        bA = __builtin_elementwise_max(bA, pA);                              \
        sB = __builtin_elementwise_max(sB, __builtin_elementwise_min(pB, bB)); \
        bB = __builtin_elementwise_max(bB, pB);                              \
    }

__global__ __launch_bounds__(BLOCK, 8)
void protein_enc_kernel(const float* __restrict__ coords,
                        const int*   __restrict__ atypes,
                        const int*   __restrict__ rtypes,
                        const float* __restrict__ tpw,
                        const float* __restrict__ aemb,
                        const float* __restrict__ remb,
                        float* __restrict__ out)
{
    __shared__ float4 pts[NN];          // 64 KB: x, y, z, -n2/2
    __shared__ float  sW[8 * 32];
    __shared__ int    sel[WPB * 64];    // 4 KB: [wave][q][r] selected indices

    const int tid  = threadIdx.x;
    const int lane = tid & 63;
    const int wv   = tid >> 6;
    const int bpb  = NN / QPB;
    const int batch    = blockIdx.x / bpb;
    const int nodeBase = (blockIdx.x % bpb) * QPB;

    const float* cb = coords + (size_t)batch * NN * 3;

    // ---- staging: contiguous float4 writes (conflict-free) ----
    for (int p = tid; p < NN; p += BLOCK) {
        float x = cb[3*p], y = cb[3*p+1], z = cb[3*p+2];
        pts[p] = make_float4(x, y, z, -0.5f * (x*x + y*y + z*z));
    }
    if (tid < 256) sW[tid] = tpw[tid];
    sel[wv * 64 + lane] = -1;           // wave-private init, no barrier needed
    __syncthreads();

    const int q0 = nodeBase + wv * QPW;          // this wave's 4 query nodes
    const float4 P0 = pts[q0],   P1 = pts[q0+1];
    const float4 P2 = pts[q0+2], P3 = pts[q0+3];
    const float x0 = P0.x, y0 = P0.y, z0 = P0.z;
    const float x1 = P1.x, y1 = P1.y, z1 = P1.z;
    const float x2 = P2.x, y2 = P2.y, z2 = P2.z;
    const float x3 = P3.x, y3 = P3.y, z3 = P3.z;

    const f32x2 qAx = {x0, x1}, qAy = {y0, y1}, qAz = {z0, z1};
    const f32x2 qBx = {x2, x3}, qBy = {y2, y3}, qBz = {z2, z3};
    const i32x2 M2v = {(int)PACKM, (int)PACKM};

    // ---- phase 1: diagonal scan; 4-deep double-buffered LDS pipeline ----
    f32x2 bA = {NEGB, NEGB}, sA = {NEGB, NEGB};
    f32x2 bB = {NEGB, NEGB}, sB = {NEGB, NEGB};

    {
        float4 Qa[4], Qb[4];
        LOAD4(Qa, 0)
        #pragma unroll 1
        for (int cg = 0; cg < 14; cg += 2) {
            LOAD4(Qb, cg + 1)
            COMP4(Qa, cg)
            LOAD4(Qa, cg + 2)
            COMP4(Qb, cg + 1)
        }
        LOAD4(Qb, 15)
        COMP4(Qa, 14)
        COMP4(Qb, 15)
    }

    float b0 = bA.x, b1 = bA.y, b2 = bB.x, b3 = bB.y;
    float s0 = sA.x, s1 = sA.y, s2 = sB.x, s3 = sB.y;

    SELFFIX(0, b0, s0)
    SELFFIX(1, b1, s1)
    SELFFIX(2, b2, s2)
    SELFFIX(3, b3, s3)

    // ---- redistribute: query q -> lanes 16q..16q+15; lane t owns columns
    //      {t, t+16, t+32, t+48} as slots 0..3 ----
    const int q  = lane >> 4;
    const int gt = lane & 15;
    float pb0, pb1, pb2, pb3, ps0, ps1, ps2, ps3;
    {
        const int ab = gt << 2;     // byte addr of source lane (column id)
#define PULL(K, PB, PS)                                                      \
        {   int a = ab + ((K) << 6);                                         \
            PB = sel4f(bpermf(a,b0), bpermf(a,b1), bpermf(a,b2), bpermf(a,b3), q); \
            PS = sel4f(bpermf(a,s0), bpermf(a,s1), bpermf(a,s2), bpermf(a,s3), q); \
        }
        PULL(0, pb0, ps0)
        PULL(1, pb1, ps1)
        PULL(2, pb2, ps2)
        PULL(3, pb3, ps3)
#undef PULL
    }

    // ---- phase 2: 16 rounds; f-only row reduce + owner-claim ----
    const unsigned long long gmask = 0xFFFFull << (q << 4);
    const int selbase = wv * 64 + (q << 4);

    #pragma unroll 1
    for (int r = 0; r < KNEI; ++r) {
        float f = fmaxf(fmaxf(pb0, pb1), fmaxf(pb2, pb3));
        f = rmax_step<0x121>(f); f = rmax_step<0x122>(f);
        f = rmax_step<0x124>(f); f = rmax_step<0x128>(f);
        // owner claim: bit-exact match against the row max
        bool c0 = (pb0 == f), c1 = (pb1 == f), c2 = (pb2 == f), c3 = (pb3 == f);
        unsigned long long m = __ballot(c0 | c1 | c2 | c3);
        int w = __ffsll(m & gmask) - 1;
        bool iwin = (lane == w);
        int kf = c0 ? 0 : (c1 ? 1 : (c2 ? 2 : 3));       // priority slot
        bool o0 = iwin && c0;
        bool o1 = iwin && !c0 && c1;
        bool o2 = iwin && !c0 && !c1 && c2;
        bool o3 = iwin && !c0 && !c1 && !c2;
        int cw  = __float_as_int(f) & 63;                // winner's row
        int col = gt + (kf << 4);                        // valid at owner
        int jw  = (cw << 6) | (col ^ cw);
        if (iwin) sel[selbase + r] = jw;
        float pskf = o1 ? ps1 : (o2 ? ps2 : (o3 ? ps3 : ps0));
        bool e = iwin && (pskf == NEGB);
        pb0 = o0 ? ps0 : pb0;  ps0 = o0 ? NEGB : ps0;
        pb1 = o1 ? ps1 : pb1;  ps1 = o1 ? NEGB : ps1;
        pb2 = o2 ? ps2 : pb2;  ps2 = o2 ? NEGB : ps2;
        pb3 = o3 ? ps3 : pb3;  ps3 = o3 ? NEGB : ps3;
        unsigned long long ex = __ballot(e);
        if (ex) {                                 // rare refill path
            if ((ex >>  0) & 0xFFFFull) REPLAY(0, x0, y0, z0)
            if ((ex >> 16) & 0xFFFFull) REPLAY(1, x1, y1, z1)
            if ((ex >> 32) & 0xFFFFull) REPLAY(2, x2, y2, z2)
            if ((ex >> 48) & 0xFFFFull) REPLAY(3, x3, y3, z3)
        }
    }

    // ---- epilogue: lane (16q+gt) owns edge gt of query q ----
    int selIdx = sel[wv * 64 + lane];

    float xq = (q & 2) ? ((q & 1) ? x3 : x2) : ((q & 1) ? x1 : x0);
    float yq = (q & 2) ? ((q & 1) ? y3 : y2) : ((q & 1) ? y1 : y0);
    float zq = (q & 2) ? ((q & 1) ? z3 : z2) : ((q & 1) ? z1 : z0);

    float4 P = pts[selIdx];
    float rx = P.x - xq, ry = P.y - yq, rz = P.z - zq;   // sender - receiver
    float dist = sqrtf(rx*rx + ry*ry + rz*rz);
    float inv  = 1.0f / (dist + 1e-8f);
    float hx = rx * inv, hy = ry * inv, hz = rz * inv;
    float cu = fminf(dist / 10.0f, 1.0f);
    // g[v] = exp(-32(cu - v/7)^2) = A * E^v * K[v];  2 expf instead of 8
    float A = expf(cu * cu * -32.0f);
    float E = expf(cu * (64.0f / 7.0f));
    const float K[8] = {1.0f, 0.5204501f, 0.0733697f, 0.00280164f,
                        2.897772e-05f, 8.11857e-08f, 6.16130e-11f,
                        1.2664166e-14f};
    float gg[8];
    float t = A, ssum = A;
    gg[0] = A;
    #pragma unroll
    for (int v = 1; v < 8; ++v) { t *= E; gg[v] = t * K[v]; ssum += gg[v]; }
    float is = 1.0f / ssum;
    float S[24];
    #pragma unroll
    for (int v = 0; v < 8; ++v) {
        float rbv = gg[v] * is;
        S[3*v]   = rbv * hx;
        S[3*v+1] = rbv * hy;
        S[3*v+2] = rbv * hz;
    }
    #pragma unroll
    for (int t2 = 0; t2 < 24; ++t2) S[t2] = row16_sum_dpp(S[t2]);

    float wcol[8];
    #pragma unroll
    for (int v = 0; v < 8; ++v) wcol[v] = sW[32*v + (lane & 31)];

    const float scale = 0.036084391824351613f;   // 1/(16*sqrt(3))
    const float4 z4 = make_float4(0.f, 0.f, 0.f, 0.f);

    #pragma unroll
    for (int qq = 0; qq < QPW; ++qq) {
        const int gq = batch * NN + q0 + qq;
        float sg[24];
        #pragma unroll
        for (int t2 = 0; t2 < 24; ++t2) sg[t2] = rlanef(S[t2], 16 * qq + 15);

        float* onode = out + (size_t)gq * 464;
        float4* o4 = (float4*)onode;
        if (lane < 16)       o4[lane] = z4;          // ch 0..63
        else if (lane < 36)  o4[lane + 24] = z4;     // ch 160..239

        if (lane < 32) {
            float a0 = 0.f, a1 = 0.f, a2 = 0.f;
            #pragma unroll
            for (int v = 0; v < 8; ++v) {
                a0 = fmaf(wcol[v], sg[3*v],   a0);
                a1 = fmaf(wcol[v], sg[3*v+1], a1);
                a2 = fmaf(wcol[v], sg[3*v+2], a2);
            }
            onode[64 + 3*lane]     = a0 * scale;
            onode[64 + 3*lane + 1] = a1 * scale;
            onode[64 + 3*lane + 2] = a2 * scale;
        }

        const int at = atypes[gq];
        const int rt = rtypes[gq];
        if (lane < 56) {
            float4 v = (lane < 28)
                ? ((const float4*)(aemb + 112*at))[lane]
                : ((const float4*)(remb + 112*rt))[lane - 28];
            o4[60 + lane] = v;
        }
    }
}

extern "C" void kernel_launch(void* const* d_in, const int* in_sizes, int n_in,
                              void* d_out, int out_size, void* d_ws, size_t ws_size,
                              hipStream_t stream)
{
    const float* coords = (const float*)d_in[0];
    const int*   at     = (const int*)  d_in[1];
    const int*   rt     = (const int*)  d_in[2];
    const float* tpw    = (const float*)d_in[3];
    const float* ae     = (const float*)d_in[4];
    const float* re     = (const float*)d_in[5];
    float* out = (float*)d_out;

    const int B = in_sizes[1] / NN;                  // 8
    dim3 grid(B * (NN / QPB));
    protein_enc_kernel<<<grid, BLOCK, 0, stream>>>(coords, at, rt, tpw, ae, re, out);
}